// Round 1
// baseline (10418.113 us; speedup 1.0000x reference)
//
#include <hip/hip_runtime.h>
#include <hip/hip_bf16.h>
#include <math.h>

#define EMBED 768
#define CROSS 512
#define HEADS 12
#define HDIM  64
#define FFN_DIM 3072
#define BATCH 8
#define SEQ   1024
#define CTX   256
#define LN_EPS 1e-5f

// ---------------------------------------------------------------------------
// LayerNorm over last dim (768). One block (256 threads) per row.
// ---------------------------------------------------------------------------
__global__ __launch_bounds__(256) void ln_kernel(
    const float* __restrict__ x, const float* __restrict__ g,
    const float* __restrict__ beta, float* __restrict__ y)
{
    __shared__ float red[256];
    const size_t row = blockIdx.x;
    const float* xr = x + row * EMBED;
    const int t = threadIdx.x;

    float v0 = xr[t], v1 = xr[t + 256], v2 = xr[t + 512];

    red[t] = v0 + v1 + v2;
    __syncthreads();
    for (int off = 128; off > 0; off >>= 1) {
        if (t < off) red[t] += red[t + off];
        __syncthreads();
    }
    const float mu = red[0] * (1.0f / (float)EMBED);
    __syncthreads();

    const float d0 = v0 - mu, d1 = v1 - mu, d2 = v2 - mu;
    red[t] = d0 * d0 + d1 * d1 + d2 * d2;
    __syncthreads();
    for (int off = 128; off > 0; off >>= 1) {
        if (t < off) red[t] += red[t + off];
        __syncthreads();
    }
    const float var = red[0] * (1.0f / (float)EMBED);
    const float rstd = rsqrtf(var + LN_EPS);

    float* yr = y + row * EMBED;
    yr[t]       = d0 * rstd * g[t]       + beta[t];
    yr[t + 256] = d1 * rstd * g[t + 256] + beta[t + 256];
    yr[t + 512] = d2 * rstd * g[t + 512] + beta[t + 512];
}

// ---------------------------------------------------------------------------
// Tiled fp32 GEMM: C[M,N] = A[M,K] @ W[K,N] + bias[N] (+ resid) (+ gelu)
// 64x64 tile, BK=16, 256 threads, 4x4 microtile per thread.
// All of M,N divisible by 64 and K divisible by 16 in this problem.
// ---------------------------------------------------------------------------
__device__ __forceinline__ float gelu_f(float x) {
    const float c = 0.7978845608028654f;  // sqrt(2/pi)
    return 0.5f * x * (1.0f + tanhf(c * (x + 0.044715f * x * x * x)));
}

template <bool GELU>
__global__ __launch_bounds__(256) void gemm64_kernel(
    const float* __restrict__ A, const float* __restrict__ W,
    const float* __restrict__ bias, const float* __restrict__ resid,
    float* __restrict__ C, int M, int N, int K)
{
    __shared__ float As[16][64];   // As[k][m]
    __shared__ float Bs[16][64];   // Bs[k][n]

    const int t  = threadIdx.x;
    const int tx = t & 15;         // n quadrant
    const int ty = t >> 4;         // m quadrant
    const int m0 = blockIdx.y * 64;
    const int n0 = blockIdx.x * 64;

    float acc[4][4] = {};

    const int arow = t >> 2, ac4 = t & 3;       // A-tile load coords
    const int brow = t >> 4, bc4 = t & 15;      // W-tile load coords

    for (int k0 = 0; k0 < K; k0 += 16) {
        {
            const float4 a4 = *(const float4*)(A + (size_t)(m0 + arow) * K + k0 + ac4 * 4);
            As[ac4 * 4 + 0][arow] = a4.x;
            As[ac4 * 4 + 1][arow] = a4.y;
            As[ac4 * 4 + 2][arow] = a4.z;
            As[ac4 * 4 + 3][arow] = a4.w;
        }
        {
            const float4 b4 = *(const float4*)(W + (size_t)(k0 + brow) * N + n0 + bc4 * 4);
            *(float4*)&Bs[brow][bc4 * 4] = b4;
        }
        __syncthreads();
#pragma unroll
        for (int kk = 0; kk < 16; ++kk) {
            float a[4];
            float b[4];
#pragma unroll
            for (int i = 0; i < 4; ++i) a[i] = As[kk][ty * 4 + i];
            const float4 b4 = *(const float4*)&Bs[kk][tx * 4];
            b[0] = b4.x; b[1] = b4.y; b[2] = b4.z; b[3] = b4.w;
#pragma unroll
            for (int i = 0; i < 4; ++i)
#pragma unroll
                for (int j = 0; j < 4; ++j) acc[i][j] += a[i] * b[j];
        }
        __syncthreads();
    }

    const float4 bia = *(const float4*)(bias + n0 + tx * 4);
#pragma unroll
    for (int i = 0; i < 4; ++i) {
        const size_t ridx = (size_t)(m0 + ty * 4 + i) * N + n0 + tx * 4;
        float4 v;
        v.x = acc[i][0] + bia.x;
        v.y = acc[i][1] + bia.y;
        v.z = acc[i][2] + bia.z;
        v.w = acc[i][3] + bia.w;
        if (resid) {
            const float4 r = *(const float4*)(resid + ridx);
            v.x += r.x; v.y += r.y; v.z += r.z; v.w += r.w;
        }
        if (GELU) {
            v.x = gelu_f(v.x); v.y = gelu_f(v.y); v.z = gelu_f(v.z); v.w = gelu_f(v.w);
        }
        *(float4*)(C + ridx) = v;
    }
}

// ---------------------------------------------------------------------------
// Fused attention: one block (256 threads) per (q, h, b).
// Q is [B*Sq, 768] (head h at col h*64), K/V are [B*Sk, 768].
// bias is [H, Sq, Sk]. Scores row kept in LDS (Sk <= 1024).
// O written in [B*Sq, 768] head-concat layout.
// ---------------------------------------------------------------------------
__global__ __launch_bounds__(256) void attn_kernel(
    const float* __restrict__ Q, const float* __restrict__ K,
    const float* __restrict__ V, const float* __restrict__ bias,
    float* __restrict__ O, int Sq, int Sk, float scale)
{
    __shared__ float sc[1024];
    __shared__ float qs[64];
    __shared__ float red[256];

    const int q = blockIdx.x, h = blockIdx.y, b = blockIdx.z;
    const int t = threadIdx.x;

    const float* qptr = Q + ((size_t)b * Sq + q) * EMBED + h * HDIM;
    if (t < 64) qs[t] = qptr[t];
    __syncthreads();

    const float* bptr = bias + ((size_t)h * Sq + q) * Sk;
    float lmax = -1e30f;
    for (int k = t; k < Sk; k += 256) {
        const float* kptr = K + ((size_t)b * Sk + k) * EMBED + h * HDIM;
        float dot = 0.0f;
#pragma unroll
        for (int d = 0; d < HDIM; ++d) dot += qs[d] * kptr[d];
        const float s = dot * scale + bptr[k];
        sc[k] = s;
        lmax = fmaxf(lmax, s);
    }

    red[t] = lmax;
    __syncthreads();
    for (int off = 128; off > 0; off >>= 1) {
        if (t < off) red[t] = fmaxf(red[t], red[t + off]);
        __syncthreads();
    }
    const float m = red[0];
    __syncthreads();

    float lsum = 0.0f;
    for (int k = t; k < Sk; k += 256) {
        const float e = __expf(sc[k] - m);
        sc[k] = e;
        lsum += e;
    }
    red[t] = lsum;
    __syncthreads();
    for (int off = 128; off > 0; off >>= 1) {
        if (t < off) red[t] += red[t + off];
        __syncthreads();
    }
    const float inv = 1.0f / red[0];
    __syncthreads();

    // PV: thread t handles d = t&63, key partition t>>6 (4 partitions)
    const int d = t & 63, part = t >> 6;
    float acc = 0.0f;
    for (int k = part; k < Sk; k += 4) {
        acc += sc[k] * V[((size_t)b * Sk + k) * EMBED + h * HDIM + d];
    }
    red[t] = acc;
    __syncthreads();
    if (t < 64) {
        const float o = (red[t] + red[t + 64] + red[t + 128] + red[t + 192]) * inv;
        O[((size_t)b * Sq + q) * EMBED + h * HDIM + t] = o;
    }
}

// ---------------------------------------------------------------------------
// Launch
// ---------------------------------------------------------------------------
extern "C" void kernel_launch(void* const* d_in, const int* in_sizes, int n_in,
                              void* d_out, int out_size, void* d_ws, size_t ws_size,
                              hipStream_t stream)
{
    const float* hidden  = (const float*)d_in[0];
    const float* context = (const float*)d_in[1];
    const float* cn_g = (const float*)d_in[2];
    const float* cn_b = (const float*)d_in[3];
    const float* wq_c = (const float*)d_in[4];
    const float* bq_c = (const float*)d_in[5];
    const float* wk_c = (const float*)d_in[6];
    const float* bk_c = (const float*)d_in[7];
    const float* wv_c = (const float*)d_in[8];
    const float* bv_c = (const float*)d_in[9];
    const float* wo_c = (const float*)d_in[10];
    const float* bo_c = (const float*)d_in[11];
    const float* bias_c = (const float*)d_in[12];
    const float* sn_g = (const float*)d_in[13];
    const float* sn_b = (const float*)d_in[14];
    const float* wq_s = (const float*)d_in[15];
    const float* bq_s = (const float*)d_in[16];
    const float* wk_s = (const float*)d_in[17];
    const float* bk_s = (const float*)d_in[18];
    const float* wv_s = (const float*)d_in[19];
    const float* bv_s = (const float*)d_in[20];
    const float* wo_s = (const float*)d_in[21];
    const float* bo_s = (const float*)d_in[22];
    const float* bias_s = (const float*)d_in[23];
    const float* fn_g = (const float*)d_in[24];
    const float* fn_b = (const float*)d_in[25];
    const float* w1 = (const float*)d_in[26];
    const float* b1 = (const float*)d_in[27];
    const float* w2 = (const float*)d_in[28];
    const float* b2 = (const float*)d_in[29];

    const size_t NTOK = (size_t)BATCH * SEQ;   // 8192
    const size_t NCTX = (size_t)BATCH * CTX;   // 2048
    const size_t TE = NTOK * EMBED;            // 6291456 floats

    float* hbuf = (float*)d_ws;
    float* xbuf = hbuf + TE;
    float* qbuf = xbuf + TE;
    float* kbuf = qbuf + TE;
    float* vbuf = kbuf + TE;
    float* obuf = vbuf + TE;
    float* fbuf = qbuf;   // FFN intermediate [8192,3072] aliases q..o (4*TE)
    float* out  = (float*)d_out;

    const dim3 blk(256);
    const float scale = 0.125f;  // 1/sqrt(64)

    // ---- cross attention block ----
    ln_kernel<<<(int)NTOK, blk, 0, stream>>>(hidden, cn_g, cn_b, xbuf);
    gemm64_kernel<false><<<dim3(EMBED / 64, NTOK / 64), blk, 0, stream>>>(
        xbuf, wq_c, bq_c, nullptr, qbuf, NTOK, EMBED, EMBED);
    gemm64_kernel<false><<<dim3(EMBED / 64, NCTX / 64), blk, 0, stream>>>(
        context, wk_c, bk_c, nullptr, kbuf, NCTX, EMBED, CROSS);
    gemm64_kernel<false><<<dim3(EMBED / 64, NCTX / 64), blk, 0, stream>>>(
        context, wv_c, bv_c, nullptr, vbuf, NCTX, EMBED, CROSS);
    attn_kernel<<<dim3(SEQ, HEADS, BATCH), blk, 0, stream>>>(
        qbuf, kbuf, vbuf, bias_c, obuf, SEQ, CTX, scale);
    gemm64_kernel<false><<<dim3(EMBED / 64, NTOK / 64), blk, 0, stream>>>(
        obuf, wo_c, bo_c, hidden, hbuf, NTOK, EMBED, EMBED);

    // ---- self attention block ----
    ln_kernel<<<(int)NTOK, blk, 0, stream>>>(hbuf, sn_g, sn_b, xbuf);
    gemm64_kernel<false><<<dim3(EMBED / 64, NTOK / 64), blk, 0, stream>>>(
        xbuf, wq_s, bq_s, nullptr, qbuf, NTOK, EMBED, EMBED);
    gemm64_kernel<false><<<dim3(EMBED / 64, NTOK / 64), blk, 0, stream>>>(
        xbuf, wk_s, bk_s, nullptr, kbuf, NTOK, EMBED, EMBED);
    gemm64_kernel<false><<<dim3(EMBED / 64, NTOK / 64), blk, 0, stream>>>(
        xbuf, wv_s, bv_s, nullptr, vbuf, NTOK, EMBED, EMBED);
    attn_kernel<<<dim3(SEQ, HEADS, BATCH), blk, 0, stream>>>(
        qbuf, kbuf, vbuf, bias_s, obuf, SEQ, SEQ, scale);
    gemm64_kernel<false><<<dim3(EMBED / 64, NTOK / 64), blk, 0, stream>>>(
        obuf, wo_s, bo_s, hbuf, hbuf, NTOK, EMBED, EMBED);  // in-place resid OK (1:1)

    // ---- FFN ----
    ln_kernel<<<(int)NTOK, blk, 0, stream>>>(hbuf, fn_g, fn_b, xbuf);
    gemm64_kernel<true><<<dim3(FFN_DIM / 64, NTOK / 64), blk, 0, stream>>>(
        xbuf, w1, b1, nullptr, fbuf, NTOK, FFN_DIM, EMBED);
    gemm64_kernel<false><<<dim3(EMBED / 64, NTOK / 64), blk, 0, stream>>>(
        fbuf, w2, b2, nullptr, out, NTOK, EMBED, FFN_DIM);
}

// Round 3
// 2711.531 us; speedup vs baseline: 3.8422x; 3.8422x over previous
//
#include <hip/hip_runtime.h>
#include <hip/hip_bf16.h>
#include <math.h>

#define EMBED 768
#define CROSS 512
#define HEADS 12
#define HDIM  64
#define FFN_DIM 3072
#define BATCH 8
#define SEQ   1024
#define CTX   256
#define LN_EPS 1e-5f

// ---------------------------------------------------------------------------
// LayerNorm over last dim (768). One block (256 threads) per row.
// ---------------------------------------------------------------------------
__global__ __launch_bounds__(256) void ln_kernel(
    const float* __restrict__ x, const float* __restrict__ g,
    const float* __restrict__ beta, float* __restrict__ y)
{
    __shared__ float red[256];
    const size_t row = blockIdx.x;
    const float* xr = x + row * EMBED;
    const int t = threadIdx.x;

    float v0 = xr[t], v1 = xr[t + 256], v2 = xr[t + 512];

    red[t] = v0 + v1 + v2;
    __syncthreads();
    for (int off = 128; off > 0; off >>= 1) {
        if (t < off) red[t] += red[t + off];
        __syncthreads();
    }
    const float mu = red[0] * (1.0f / (float)EMBED);
    __syncthreads();

    const float d0 = v0 - mu, d1 = v1 - mu, d2 = v2 - mu;
    red[t] = d0 * d0 + d1 * d1 + d2 * d2;
    __syncthreads();
    for (int off = 128; off > 0; off >>= 1) {
        if (t < off) red[t] += red[t + off];
        __syncthreads();
    }
    const float var = red[0] * (1.0f / (float)EMBED);
    const float rstd = rsqrtf(var + LN_EPS);

    float* yr = y + row * EMBED;
    yr[t]       = d0 * rstd * g[t]       + beta[t];
    yr[t + 256] = d1 * rstd * g[t + 256] + beta[t + 256];
    yr[t + 512] = d2 * rstd * g[t + 512] + beta[t + 512];
}

// ---------------------------------------------------------------------------
// Tiled fp32 GEMM: C[M,N] = A[M,K] @ W[K,N] + bias[N] (+ resid) (+ gelu)
// 64x64 tile, BK=16, 256 threads, 4x4 microtile per thread.
// ---------------------------------------------------------------------------
__device__ __forceinline__ float gelu_f(float x) {
    const float c = 0.7978845608028654f;  // sqrt(2/pi)
    return 0.5f * x * (1.0f + tanhf(c * (x + 0.044715f * x * x * x)));
}

template <bool GELU>
__global__ __launch_bounds__(256) void gemm64_kernel(
    const float* __restrict__ A, const float* __restrict__ W,
    const float* __restrict__ bias, const float* __restrict__ resid,
    float* __restrict__ C, int M, int N, int K)
{
    __shared__ float As[16][64];   // As[k][m]
    __shared__ float Bs[16][64];   // Bs[k][n]

    const int t  = threadIdx.x;
    const int tx = t & 15;         // n quadrant
    const int ty = t >> 4;         // m quadrant
    const int m0 = blockIdx.y * 64;
    const int n0 = blockIdx.x * 64;

    float acc[4][4] = {};

    const int arow = t >> 2, ac4 = t & 3;       // A-tile load coords
    const int brow = t >> 4, bc4 = t & 15;      // W-tile load coords

    for (int k0 = 0; k0 < K; k0 += 16) {
        {
            const float4 a4 = *(const float4*)(A + (size_t)(m0 + arow) * K + k0 + ac4 * 4);
            As[ac4 * 4 + 0][arow] = a4.x;
            As[ac4 * 4 + 1][arow] = a4.y;
            As[ac4 * 4 + 2][arow] = a4.z;
            As[ac4 * 4 + 3][arow] = a4.w;
        }
        {
            const float4 b4 = *(const float4*)(W + (size_t)(k0 + brow) * N + n0 + bc4 * 4);
            *(float4*)&Bs[brow][bc4 * 4] = b4;
        }
        __syncthreads();
#pragma unroll
        for (int kk = 0; kk < 16; ++kk) {
            float a[4];
            float b[4];
#pragma unroll
            for (int i = 0; i < 4; ++i) a[i] = As[kk][ty * 4 + i];
            const float4 b4 = *(const float4*)&Bs[kk][tx * 4];
            b[0] = b4.x; b[1] = b4.y; b[2] = b4.z; b[3] = b4.w;
#pragma unroll
            for (int i = 0; i < 4; ++i)
#pragma unroll
                for (int j = 0; j < 4; ++j) acc[i][j] += a[i] * b[j];
        }
        __syncthreads();
    }

    const float4 bia = *(const float4*)(bias + n0 + tx * 4);
#pragma unroll
    for (int i = 0; i < 4; ++i) {
        const size_t ridx = (size_t)(m0 + ty * 4 + i) * N + n0 + tx * 4;
        float4 v;
        v.x = acc[i][0] + bia.x;
        v.y = acc[i][1] + bia.y;
        v.z = acc[i][2] + bia.z;
        v.w = acc[i][3] + bia.w;
        if (resid) {
            const float4 r = *(const float4*)(resid + ridx);
            v.x += r.x; v.y += r.y; v.z += r.z; v.w += r.w;
        }
        if (GELU) {
            v.x = gelu_f(v.x); v.y = gelu_f(v.y); v.z = gelu_f(v.z); v.w = gelu_f(v.w);
        }
        *(float4*)(C + ridx) = v;
    }
}

// ---------------------------------------------------------------------------
// Flash-style fp32 attention.
// One block = 64-query tile of one (b,h). 256 threads.
// Q/K/V in [B*T, 768] head-concat layout (head h at col h*64).
// bias is [H, Sq, Sk]. Online softmax; P reuses K's LDS buffer.
// Thread map (QK):  q rows {tq+16i}, k cols {tk+16j}, tq=t>>4, tk=t&15.
// Thread map (PV):  q rows {tq+16i}, d cols {4*tk+j}.   (same tq -> m/l local)
// grid.x = BATCH * (Sq/64) with batch FASTEST (bias L2/L3 reuse), grid.y = H.
// ---------------------------------------------------------------------------
template <int SK>
__global__ __launch_bounds__(256) void flash_attn_kernel(
    const float* __restrict__ Q, const float* __restrict__ K,
    const float* __restrict__ V, const float* __restrict__ bias,
    float* __restrict__ O, float scale)
{
    __shared__ float Qs[64][68];
    __shared__ float KPs[64][68];   // K tile, then P tile
    __shared__ float Vs[64][68];

    const int t  = threadIdx.x;
    const int b  = blockIdx.x & 7;          // batch fastest
    const int qt = blockIdx.x >> 3;
    const int h  = blockIdx.y;
    const int q0 = qt * 64;

    const int tq = t >> 4;                  // 0..15
    const int tk = t & 15;                  // 0..15

    // ---- load Q tile: row r=t>>2, 16-float chunk (t&3) ----
    {
        const int r = t >> 2, c0 = (t & 3) * 16;
        const float* src = Q + ((size_t)(b * SEQ) + q0 + r) * EMBED + h * HDIM + c0;
#pragma unroll
        for (int c = 0; c < 4; ++c)
            *(float4*)&Qs[r][c0 + c * 4] = *(const float4*)(src + c * 4);
    }

    float m[4], l[4], o[4][4];
#pragma unroll
    for (int i = 0; i < 4; ++i) {
        m[i] = -1e30f; l[i] = 0.0f;
#pragma unroll
        for (int j = 0; j < 4; ++j) o[i][j] = 0.0f;
    }

    const float* bptr = bias + ((size_t)h * SEQ + q0) * SK;
    __syncthreads();

    for (int k0 = 0; k0 < SK; k0 += 64) {
        // ---- load K,V tiles ----
        {
            const int r = t >> 2, c0 = (t & 3) * 16;
            const float* ks = K + ((size_t)(b * SK) + k0 + r) * EMBED + h * HDIM + c0;
            const float* vs = V + ((size_t)(b * SK) + k0 + r) * EMBED + h * HDIM + c0;
#pragma unroll
            for (int c = 0; c < 4; ++c) {
                *(float4*)&KPs[r][c0 + c * 4] = *(const float4*)(ks + c * 4);
                *(float4*)&Vs[r][c0 + c * 4]  = *(const float4*)(vs + c * 4);
            }
        }

        // ---- prefetch bias for this tile into registers ----
        float breg[4][4];
#pragma unroll
        for (int i = 0; i < 4; ++i)
#pragma unroll
            for (int j = 0; j < 4; ++j)
                breg[i][j] = bptr[(size_t)(tq + 16 * i) * SK + k0 + tk + 16 * j];

        __syncthreads();

        // ---- QK^T microtile ----
        float s[4][4] = {};
#pragma unroll
        for (int db = 0; db < 64; db += 4) {
            float4 qv[4], kv[4];
#pragma unroll
            for (int i = 0; i < 4; ++i) qv[i] = *(const float4*)&Qs[tq + 16 * i][db];
#pragma unroll
            for (int j = 0; j < 4; ++j) kv[j] = *(const float4*)&KPs[tk + 16 * j][db];
#pragma unroll
            for (int i = 0; i < 4; ++i)
#pragma unroll
                for (int j = 0; j < 4; ++j)
                    s[i][j] += qv[i].x * kv[j].x + qv[i].y * kv[j].y +
                               qv[i].z * kv[j].z + qv[i].w * kv[j].w;
        }

        // ---- online softmax (register + shfl within 16-lane row group) ----
        float corr[4];
#pragma unroll
        for (int i = 0; i < 4; ++i) {
            float tmax = -1e30f;
#pragma unroll
            for (int j = 0; j < 4; ++j) {
                s[i][j] = s[i][j] * scale + breg[i][j];
                tmax = fmaxf(tmax, s[i][j]);
            }
            tmax = fmaxf(tmax, __shfl_xor(tmax, 1));
            tmax = fmaxf(tmax, __shfl_xor(tmax, 2));
            tmax = fmaxf(tmax, __shfl_xor(tmax, 4));
            tmax = fmaxf(tmax, __shfl_xor(tmax, 8));
            const float mnew = fmaxf(m[i], tmax);
            corr[i] = __expf(m[i] - mnew);
            float psum = 0.0f;
#pragma unroll
            for (int j = 0; j < 4; ++j) {
                const float p = __expf(s[i][j] - mnew);
                s[i][j] = p;
                psum += p;
            }
            psum += __shfl_xor(psum, 1);
            psum += __shfl_xor(psum, 2);
            psum += __shfl_xor(psum, 4);
            psum += __shfl_xor(psum, 8);
            l[i] = l[i] * corr[i] + psum;
            m[i] = mnew;
#pragma unroll
            for (int j = 0; j < 4; ++j) o[i][j] *= corr[i];
        }

        __syncthreads();   // all QK reads of KPs done

        // ---- write P into KPs ----
#pragma unroll
        for (int i = 0; i < 4; ++i)
#pragma unroll
            for (int j = 0; j < 4; ++j)
                KPs[tq + 16 * i][tk + 16 * j] = s[i][j];

        __syncthreads();

        // ---- PV: d cols {4*tk..4*tk+3} ----
#pragma unroll 4
        for (int k = 0; k < 64; ++k) {
            const float4 vv = *(const float4*)&Vs[k][4 * tk];
#pragma unroll
            for (int i = 0; i < 4; ++i) {
                const float p = KPs[tq + 16 * i][k];
                o[i][0] += p * vv.x;
                o[i][1] += p * vv.y;
                o[i][2] += p * vv.z;
                o[i][3] += p * vv.w;
            }
        }

        __syncthreads();   // PV reads done before next tile overwrites
    }

    // ---- finalize + store ----
#pragma unroll
    for (int i = 0; i < 4; ++i) {
        const float inv = 1.0f / l[i];
        float4 v;
        v.x = o[i][0] * inv; v.y = o[i][1] * inv;
        v.z = o[i][2] * inv; v.w = o[i][3] * inv;
        *(float4*)(O + ((size_t)(b * SEQ) + q0 + tq + 16 * i) * EMBED + h * HDIM + 4 * tk) = v;
    }
}

// ---------------------------------------------------------------------------
// Launch
// ---------------------------------------------------------------------------
extern "C" void kernel_launch(void* const* d_in, const int* in_sizes, int n_in,
                              void* d_out, int out_size, void* d_ws, size_t ws_size,
                              hipStream_t stream)
{
    const float* hidden  = (const float*)d_in[0];
    const float* context = (const float*)d_in[1];
    const float* cn_g = (const float*)d_in[2];
    const float* cn_b = (const float*)d_in[3];
    const float* wq_c = (const float*)d_in[4];
    const float* bq_c = (const float*)d_in[5];
    const float* wk_c = (const float*)d_in[6];
    const float* bk_c = (const float*)d_in[7];
    const float* wv_c = (const float*)d_in[8];
    const float* bv_c = (const float*)d_in[9];
    const float* wo_c = (const float*)d_in[10];
    const float* bo_c = (const float*)d_in[11];
    const float* bias_c = (const float*)d_in[12];
    const float* sn_g = (const float*)d_in[13];
    const float* sn_b = (const float*)d_in[14];
    const float* wq_s = (const float*)d_in[15];
    const float* bq_s = (const float*)d_in[16];
    const float* wk_s = (const float*)d_in[17];
    const float* bk_s = (const float*)d_in[18];
    const float* wv_s = (const float*)d_in[19];
    const float* bv_s = (const float*)d_in[20];
    const float* wo_s = (const float*)d_in[21];
    const float* bo_s = (const float*)d_in[22];
    const float* bias_s = (const float*)d_in[23];
    const float* fn_g = (const float*)d_in[24];
    const float* fn_b = (const float*)d_in[25];
    const float* w1 = (const float*)d_in[26];
    const float* b1 = (const float*)d_in[27];
    const float* w2 = (const float*)d_in[28];
    const float* b2 = (const float*)d_in[29];

    const size_t NTOK = (size_t)BATCH * SEQ;   // 8192
    const size_t NCTX = (size_t)BATCH * CTX;   // 2048
    const size_t TE = NTOK * EMBED;            // 6291456 floats

    float* hbuf = (float*)d_ws;
    float* xbuf = hbuf + TE;
    float* qbuf = xbuf + TE;
    float* kbuf = qbuf + TE;
    float* vbuf = kbuf + TE;
    float* obuf = vbuf + TE;
    float* fbuf = qbuf;   // FFN intermediate [8192,3072] aliases q..o (4*TE)
    float* out  = (float*)d_out;

    const dim3 blk(256);
    const float scale = 0.125f;  // 1/sqrt(64)
    const dim3 agrid(BATCH * (SEQ / 64), HEADS);

    // ---- cross attention block ----
    ln_kernel<<<(int)NTOK, blk, 0, stream>>>(hidden, cn_g, cn_b, xbuf);
    gemm64_kernel<false><<<dim3(EMBED / 64, NTOK / 64), blk, 0, stream>>>(
        xbuf, wq_c, bq_c, nullptr, qbuf, NTOK, EMBED, EMBED);
    gemm64_kernel<false><<<dim3(EMBED / 64, NCTX / 64), blk, 0, stream>>>(
        context, wk_c, bk_c, nullptr, kbuf, NCTX, EMBED, CROSS);
    gemm64_kernel<false><<<dim3(EMBED / 64, NCTX / 64), blk, 0, stream>>>(
        context, wv_c, bv_c, nullptr, vbuf, NCTX, EMBED, CROSS);
    flash_attn_kernel<CTX><<<agrid, blk, 0, stream>>>(
        qbuf, kbuf, vbuf, bias_c, obuf, scale);
    gemm64_kernel<false><<<dim3(EMBED / 64, NTOK / 64), blk, 0, stream>>>(
        obuf, wo_c, bo_c, hidden, hbuf, NTOK, EMBED, EMBED);

    // ---- self attention block ----
    ln_kernel<<<(int)NTOK, blk, 0, stream>>>(hbuf, sn_g, sn_b, xbuf);
    gemm64_kernel<false><<<dim3(EMBED / 64, NTOK / 64), blk, 0, stream>>>(
        xbuf, wq_s, bq_s, nullptr, qbuf, NTOK, EMBED, EMBED);
    gemm64_kernel<false><<<dim3(EMBED / 64, NTOK / 64), blk, 0, stream>>>(
        xbuf, wk_s, bk_s, nullptr, kbuf, NTOK, EMBED, EMBED);
    gemm64_kernel<false><<<dim3(EMBED / 64, NTOK / 64), blk, 0, stream>>>(
        xbuf, wv_s, bv_s, nullptr, vbuf, NTOK, EMBED, EMBED);
    flash_attn_kernel<SEQ><<<agrid, blk, 0, stream>>>(
        qbuf, kbuf, vbuf, bias_s, obuf, scale);
    gemm64_kernel<false><<<dim3(EMBED / 64, NTOK / 64), blk, 0, stream>>>(
        obuf, wo_s, bo_s, hbuf, hbuf, NTOK, EMBED, EMBED);  // in-place resid OK (1:1)

    // ---- FFN ----
    ln_kernel<<<(int)NTOK, blk, 0, stream>>>(hbuf, fn_g, fn_b, xbuf);
    gemm64_kernel<true><<<dim3(FFN_DIM / 64, NTOK / 64), blk, 0, stream>>>(
        xbuf, w1, b1, nullptr, fbuf, NTOK, FFN_DIM, EMBED);
    gemm64_kernel<false><<<dim3(EMBED / 64, NTOK / 64), blk, 0, stream>>>(
        fbuf, w2, b2, nullptr, out, NTOK, EMBED, FFN_DIM);
}

// Round 4
// 1169.106 us; speedup vs baseline: 8.9112x; 2.3193x over previous
//
#include <hip/hip_runtime.h>
#include <hip/hip_bf16.h>
#include <math.h>

#define EMBED 768
#define CROSS 512
#define HEADS 12
#define HDIM  64
#define FFN_DIM 3072
#define BATCH 8
#define SEQ   1024
#define CTX   256
#define LN_EPS 1e-5f

using f32x4 = __attribute__((ext_vector_type(4))) float;
using s16x8 = __attribute__((ext_vector_type(8))) short;   // 8 bf16 in 4 VGPRs

// float -> bf16 (RNE), bit-trick
__device__ __forceinline__ unsigned short f2bf(float f) {
    union { float f; unsigned u; } x{f};
    const unsigned r = x.u + 0x7fffu + ((x.u >> 16) & 1u);
    return (unsigned short)(r >> 16);
}

__device__ __forceinline__ void gl16(const void* g, void* l) {
    __builtin_amdgcn_global_load_lds(
        (const __attribute__((address_space(1))) void*)g,
        (__attribute__((address_space(3))) void*)l, 16, 0, 0);
}

__device__ __forceinline__ float gelu_f(float x) {
    const float c = 0.7978845608028654f;  // sqrt(2/pi)
    return 0.5f * x * (1.0f + tanhf(c * (x + 0.044715f * x * x * x)));
}

// ---------------------------------------------------------------------------
// Weight prep: W[K,N] fp32 -> WT[N,K] bf16 (transposed, K-contiguous)
// ---------------------------------------------------------------------------
__global__ __launch_bounds__(256) void transpose_cast_kernel(
    const float* __restrict__ W, unsigned short* __restrict__ WT, int K, int N)
{
    __shared__ float T[32][33];
    const int k0 = blockIdx.y * 32, n0 = blockIdx.x * 32;
    const int t = threadIdx.x;
    const int r = t >> 3, c4 = (t & 7) * 4;
    const float4 v = *(const float4*)(W + (size_t)(k0 + r) * N + n0 + c4);
    T[r][c4 + 0] = v.x; T[r][c4 + 1] = v.y; T[r][c4 + 2] = v.z; T[r][c4 + 3] = v.w;
    __syncthreads();
    ushort4 o;
    o.x = f2bf(T[c4 + 0][r]); o.y = f2bf(T[c4 + 1][r]);
    o.z = f2bf(T[c4 + 2][r]); o.w = f2bf(T[c4 + 3][r]);
    *(ushort4*)(WT + (size_t)(n0 + r) * K + k0 + c4) = o;
}

// elementwise fp32 -> bf16 (n divisible by 1024)
__global__ __launch_bounds__(256) void cast_bf16_kernel(
    const float* __restrict__ x, unsigned short* __restrict__ y, int n)
{
    const int i = (blockIdx.x * 256 + threadIdx.x) * 4;
    if (i < n) {
        const float4 v = *(const float4*)(x + i);
        ushort4 o{f2bf(v.x), f2bf(v.y), f2bf(v.z), f2bf(v.w)};
        *(ushort4*)(y + i) = o;
    }
}

// ---------------------------------------------------------------------------
// LayerNorm over 768, writes bf16 (GEMM A-operand). One block per row.
// ---------------------------------------------------------------------------
__global__ __launch_bounds__(256) void ln_kernel(
    const float* __restrict__ x, const float* __restrict__ g,
    const float* __restrict__ beta, unsigned short* __restrict__ y)
{
    __shared__ float red[256];
    const size_t row = blockIdx.x;
    const float* xr = x + row * EMBED;
    const int t = threadIdx.x;

    float v0 = xr[t], v1 = xr[t + 256], v2 = xr[t + 512];

    red[t] = v0 + v1 + v2;
    __syncthreads();
    for (int off = 128; off > 0; off >>= 1) {
        if (t < off) red[t] += red[t + off];
        __syncthreads();
    }
    const float mu = red[0] * (1.0f / (float)EMBED);
    __syncthreads();

    const float d0 = v0 - mu, d1 = v1 - mu, d2 = v2 - mu;
    red[t] = d0 * d0 + d1 * d1 + d2 * d2;
    __syncthreads();
    for (int off = 128; off > 0; off >>= 1) {
        if (t < off) red[t] += red[t + off];
        __syncthreads();
    }
    const float var = red[0] * (1.0f / (float)EMBED);
    const float rstd = rsqrtf(var + LN_EPS);

    unsigned short* yr = y + row * EMBED;
    yr[t]       = f2bf(d0 * rstd * g[t]       + beta[t]);
    yr[t + 256] = f2bf(d1 * rstd * g[t + 256] + beta[t + 256]);
    yr[t + 512] = f2bf(d2 * rstd * g[t + 512] + beta[t + 512]);
}

// ---------------------------------------------------------------------------
// bf16 MFMA GEMM: C[M,N] = A[M,K](bf16) @ WT[N,K](bf16)^T + bias (+resid)(+gelu)
// 128x128 tile, BK=32, 256 threads = 4 waves (2x2 of 64x64), fp32 accum.
// Staging via global_load_lds width-16; LDS rows 64B => conflict-free b128.
// mfma_f32_16x16x32_bf16 layouts: A row=l&15,k=(l>>4)*8+j ; B col=l&15 same k;
// C col=l&15, row=(l>>4)*4+reg  [m89-verified].
// ---------------------------------------------------------------------------
template <int OUT_BF16, int DO_GELU>
__global__ __launch_bounds__(256) void gemm_mfma_kernel(
    const unsigned short* __restrict__ A,   // [M,K]
    const unsigned short* __restrict__ WT,  // [N,K]
    const float* __restrict__ bias,         // [N]
    const float* __restrict__ resid,        // [M,N] or null
    void* __restrict__ Cv, int M, int N, int K)
{
    __shared__ unsigned short As[128][32];
    __shared__ unsigned short Bs[128][32];

    const int t = threadIdx.x;
    const int l = t & 63;
    const int w = t >> 6;
    const int m0 = blockIdx.y * 128;
    const int n0 = blockIdx.x * 128;
    const int wm = (w >> 1) * 64;
    const int wn = (w & 1) * 64;

    const int sr = t >> 2;          // staging row 0..63
    const int sc = t & 3;           // 16B chunk

    f32x4 acc[4][4] = {};

    const unsigned short* Ap0 = A  + (size_t)(m0 + sr) * K + sc * 8;
    const unsigned short* Ap1 = Ap0 + (size_t)64 * K;
    const unsigned short* Bp0 = WT + (size_t)(n0 + sr) * K + sc * 8;
    const unsigned short* Bp1 = Bp0 + (size_t)64 * K;

    const int fr = l & 15;
    const int kb = (l >> 4) * 8;

    for (int k0 = 0; k0 < K; k0 += 32) {
        gl16(Ap0 + k0, &As[sr][sc * 8]);
        gl16(Ap1 + k0, &As[sr + 64][sc * 8]);
        gl16(Bp0 + k0, &Bs[sr][sc * 8]);
        gl16(Bp1 + k0, &Bs[sr + 64][sc * 8]);
        __syncthreads();

        s16x8 af[4], bf[4];
#pragma unroll
        for (int i = 0; i < 4; ++i) af[i] = *(const s16x8*)&As[wm + i * 16 + fr][kb];
#pragma unroll
        for (int j = 0; j < 4; ++j) bf[j] = *(const s16x8*)&Bs[wn + j * 16 + fr][kb];
#pragma unroll
        for (int i = 0; i < 4; ++i)
#pragma unroll
            for (int j = 0; j < 4; ++j)
                acc[i][j] = __builtin_amdgcn_mfma_f32_16x16x32_bf16(
                    af[i], bf[j], acc[i][j], 0, 0, 0);
        __syncthreads();
    }

    const int rg = (l >> 4) * 4;
#pragma unroll
    for (int j = 0; j < 4; ++j) {
        const int col = n0 + wn + j * 16 + fr;
        const float bia = bias[col];
#pragma unroll
        for (int i = 0; i < 4; ++i) {
#pragma unroll
            for (int r = 0; r < 4; ++r) {
                const int row = m0 + wm + i * 16 + rg + r;
                float v = acc[i][j][r] + bia;
                if (resid) v += resid[(size_t)row * N + col];
                if (DO_GELU) v = gelu_f(v);
                if (OUT_BF16)
                    ((unsigned short*)Cv)[(size_t)row * N + col] = f2bf(v);
                else
                    ((float*)Cv)[(size_t)row * N + col] = v;
            }
        }
    }
}

// ---------------------------------------------------------------------------
// Flash-style fp32 attention (unchanged math); O written as bf16.
// ---------------------------------------------------------------------------
template <int SK>
__global__ __launch_bounds__(256) void flash_attn_kernel(
    const float* __restrict__ Q, const float* __restrict__ K,
    const float* __restrict__ V, const float* __restrict__ bias,
    unsigned short* __restrict__ O, float scale)
{
    __shared__ float Qs[64][68];
    __shared__ float KPs[64][68];
    __shared__ float Vs[64][68];

    const int t  = threadIdx.x;
    const int b  = blockIdx.x & 7;
    const int qt = blockIdx.x >> 3;
    const int h  = blockIdx.y;
    const int q0 = qt * 64;

    const int tq = t >> 4;
    const int tk = t & 15;

    {
        const int r = t >> 2, c0 = (t & 3) * 16;
        const float* src = Q + ((size_t)(b * SEQ) + q0 + r) * EMBED + h * HDIM + c0;
#pragma unroll
        for (int c = 0; c < 4; ++c)
            *(float4*)&Qs[r][c0 + c * 4] = *(const float4*)(src + c * 4);
    }

    float m[4], l[4], o[4][4];
#pragma unroll
    for (int i = 0; i < 4; ++i) {
        m[i] = -1e30f; l[i] = 0.0f;
#pragma unroll
        for (int j = 0; j < 4; ++j) o[i][j] = 0.0f;
    }

    const float* bptr = bias + ((size_t)h * SEQ + q0) * SK;
    __syncthreads();

    for (int k0 = 0; k0 < SK; k0 += 64) {
        {
            const int r = t >> 2, c0 = (t & 3) * 16;
            const float* ks = K + ((size_t)(b * SK) + k0 + r) * EMBED + h * HDIM + c0;
            const float* vs = V + ((size_t)(b * SK) + k0 + r) * EMBED + h * HDIM + c0;
#pragma unroll
            for (int c = 0; c < 4; ++c) {
                *(float4*)&KPs[r][c0 + c * 4] = *(const float4*)(ks + c * 4);
                *(float4*)&Vs[r][c0 + c * 4]  = *(const float4*)(vs + c * 4);
            }
        }

        float breg[4][4];
#pragma unroll
        for (int i = 0; i < 4; ++i)
#pragma unroll
            for (int j = 0; j < 4; ++j)
                breg[i][j] = bptr[(size_t)(tq + 16 * i) * SK + k0 + tk + 16 * j];

        __syncthreads();

        float s[4][4] = {};
#pragma unroll
        for (int db = 0; db < 64; db += 4) {
            float4 qv[4], kv[4];
#pragma unroll
            for (int i = 0; i < 4; ++i) qv[i] = *(const float4*)&Qs[tq + 16 * i][db];
#pragma unroll
            for (int j = 0; j < 4; ++j) kv[j] = *(const float4*)&KPs[tk + 16 * j][db];
#pragma unroll
            for (int i = 0; i < 4; ++i)
#pragma unroll
                for (int j = 0; j < 4; ++j)
                    s[i][j] += qv[i].x * kv[j].x + qv[i].y * kv[j].y +
                               qv[i].z * kv[j].z + qv[i].w * kv[j].w;
        }

        float corr[4];
#pragma unroll
        for (int i = 0; i < 4; ++i) {
            float tmax = -1e30f;
#pragma unroll
            for (int j = 0; j < 4; ++j) {
                s[i][j] = s[i][j] * scale + breg[i][j];
                tmax = fmaxf(tmax, s[i][j]);
            }
            tmax = fmaxf(tmax, __shfl_xor(tmax, 1));
            tmax = fmaxf(tmax, __shfl_xor(tmax, 2));
            tmax = fmaxf(tmax, __shfl_xor(tmax, 4));
            tmax = fmaxf(tmax, __shfl_xor(tmax, 8));
            const float mnew = fmaxf(m[i], tmax);
            corr[i] = __expf(m[i] - mnew);
            float psum = 0.0f;
#pragma unroll
            for (int j = 0; j < 4; ++j) {
                const float p = __expf(s[i][j] - mnew);
                s[i][j] = p;
                psum += p;
            }
            psum += __shfl_xor(psum, 1);
            psum += __shfl_xor(psum, 2);
            psum += __shfl_xor(psum, 4);
            psum += __shfl_xor(psum, 8);
            l[i] = l[i] * corr[i] + psum;
            m[i] = mnew;
#pragma unroll
            for (int j = 0; j < 4; ++j) o[i][j] *= corr[i];
        }

        __syncthreads();

#pragma unroll
        for (int i = 0; i < 4; ++i)
#pragma unroll
            for (int j = 0; j < 4; ++j)
                KPs[tq + 16 * i][tk + 16 * j] = s[i][j];

        __syncthreads();

#pragma unroll 4
        for (int k = 0; k < 64; ++k) {
            const float4 vv = *(const float4*)&Vs[k][4 * tk];
#pragma unroll
            for (int i = 0; i < 4; ++i) {
                const float p = KPs[tq + 16 * i][k];
                o[i][0] += p * vv.x;
                o[i][1] += p * vv.y;
                o[i][2] += p * vv.z;
                o[i][3] += p * vv.w;
            }
        }

        __syncthreads();
    }

#pragma unroll
    for (int i = 0; i < 4; ++i) {
        const float inv = 1.0f / l[i];
        ushort4 v;
        v.x = f2bf(o[i][0] * inv); v.y = f2bf(o[i][1] * inv);
        v.z = f2bf(o[i][2] * inv); v.w = f2bf(o[i][3] * inv);
        *(ushort4*)(O + ((size_t)(b * SEQ) + q0 + tq + 16 * i) * EMBED + h * HDIM + 4 * tk) = v;
    }
}

// ---------------------------------------------------------------------------
// Launch
// ---------------------------------------------------------------------------
extern "C" void kernel_launch(void* const* d_in, const int* in_sizes, int n_in,
                              void* d_out, int out_size, void* d_ws, size_t ws_size,
                              hipStream_t stream)
{
    const float* hidden  = (const float*)d_in[0];
    const float* context = (const float*)d_in[1];
    const float* cn_g = (const float*)d_in[2];
    const float* cn_b = (const float*)d_in[3];
    const float* wq_c = (const float*)d_in[4];
    const float* bq_c = (const float*)d_in[5];
    const float* wk_c = (const float*)d_in[6];
    const float* bk_c = (const float*)d_in[7];
    const float* wv_c = (const float*)d_in[8];
    const float* bv_c = (const float*)d_in[9];
    const float* wo_c = (const float*)d_in[10];
    const float* bo_c = (const float*)d_in[11];
    const float* bias_c = (const float*)d_in[12];
    const float* sn_g = (const float*)d_in[13];
    const float* sn_b = (const float*)d_in[14];
    const float* wq_s = (const float*)d_in[15];
    const float* bq_s = (const float*)d_in[16];
    const float* wk_s = (const float*)d_in[17];
    const float* bk_s = (const float*)d_in[18];
    const float* wv_s = (const float*)d_in[19];
    const float* bv_s = (const float*)d_in[20];
    const float* wo_s = (const float*)d_in[21];
    const float* bo_s = (const float*)d_in[22];
    const float* bias_s = (const float*)d_in[23];
    const float* fn_g = (const float*)d_in[24];
    const float* fn_b = (const float*)d_in[25];
    const float* w1 = (const float*)d_in[26];
    const float* b1 = (const float*)d_in[27];
    const float* w2 = (const float*)d_in[28];
    const float* b2 = (const float*)d_in[29];

    const size_t NTOK = (size_t)BATCH * SEQ;   // 8192
    const size_t NCTX = (size_t)BATCH * CTX;   // 2048
    const size_t TE = NTOK * EMBED;            // 6291456

    // ---- workspace layout (bytes) ----
    char* p = (char*)d_ws;
    float* hbuf = (float*)p;                 p += TE * 4;
    unsigned short* xbuf = (unsigned short*)p; p += TE * 2;
    float* qbuf = (float*)p;                 p += TE * 4;
    float* kbuf = (float*)p;                 p += TE * 4;
    float* vbuf = (float*)p;                 p += TE * 4;
    unsigned short* obuf = (unsigned short*)p; p += TE * 2;
    unsigned short* ctxb = (unsigned short*)p; p += NCTX * CROSS * 2;
    unsigned short* wt_qc = (unsigned short*)p; p += (size_t)EMBED * EMBED * 2;
    unsigned short* wt_kc = (unsigned short*)p; p += (size_t)CROSS * EMBED * 2;
    unsigned short* wt_vc = (unsigned short*)p; p += (size_t)CROSS * EMBED * 2;
    unsigned short* wt_oc = (unsigned short*)p; p += (size_t)EMBED * EMBED * 2;
    unsigned short* wt_qs = (unsigned short*)p; p += (size_t)EMBED * EMBED * 2;
    unsigned short* wt_ks = (unsigned short*)p; p += (size_t)EMBED * EMBED * 2;
    unsigned short* wt_vs = (unsigned short*)p; p += (size_t)EMBED * EMBED * 2;
    unsigned short* wt_os = (unsigned short*)p; p += (size_t)EMBED * EMBED * 2;
    unsigned short* wt_w1 = (unsigned short*)p; p += (size_t)EMBED * FFN_DIM * 2;
    unsigned short* wt_w2 = (unsigned short*)p; p += (size_t)FFN_DIM * EMBED * 2;
    unsigned short* fbuf = (unsigned short*)qbuf;  // FFN mid aliases q/k/v span
    float* out = (float*)d_out;

    const dim3 blk(256);
    const float scale = 0.125f;
    const dim3 agrid(BATCH * (SEQ / 64), HEADS);

    // ---- weight prep (every launch; no persistent state) ----
    transpose_cast_kernel<<<dim3(EMBED/32, EMBED/32), blk, 0, stream>>>(wq_c, wt_qc, EMBED, EMBED);
    transpose_cast_kernel<<<dim3(EMBED/32, CROSS/32), blk, 0, stream>>>(wk_c, wt_kc, CROSS, EMBED);
    transpose_cast_kernel<<<dim3(EMBED/32, CROSS/32), blk, 0, stream>>>(wv_c, wt_vc, CROSS, EMBED);
    transpose_cast_kernel<<<dim3(EMBED/32, EMBED/32), blk, 0, stream>>>(wo_c, wt_oc, EMBED, EMBED);
    transpose_cast_kernel<<<dim3(EMBED/32, EMBED/32), blk, 0, stream>>>(wq_s, wt_qs, EMBED, EMBED);
    transpose_cast_kernel<<<dim3(EMBED/32, EMBED/32), blk, 0, stream>>>(wk_s, wt_ks, EMBED, EMBED);
    transpose_cast_kernel<<<dim3(EMBED/32, EMBED/32), blk, 0, stream>>>(wv_s, wt_vs, EMBED, EMBED);
    transpose_cast_kernel<<<dim3(EMBED/32, EMBED/32), blk, 0, stream>>>(wo_s, wt_os, EMBED, EMBED);
    transpose_cast_kernel<<<dim3(FFN_DIM/32, EMBED/32), blk, 0, stream>>>(w1, wt_w1, EMBED, FFN_DIM);
    transpose_cast_kernel<<<dim3(EMBED/32, FFN_DIM/32), blk, 0, stream>>>(w2, wt_w2, FFN_DIM, EMBED);
    cast_bf16_kernel<<<(int)(NCTX * CROSS / 1024), blk, 0, stream>>>(
        context, ctxb, (int)(NCTX * CROSS));

    // ---- cross attention block ----
    ln_kernel<<<(int)NTOK, blk, 0, stream>>>(hidden, cn_g, cn_b, xbuf);
    gemm_mfma_kernel<0,0><<<dim3(EMBED/128, NTOK/128), blk, 0, stream>>>(
        xbuf, wt_qc, bq_c, nullptr, qbuf, NTOK, EMBED, EMBED);
    gemm_mfma_kernel<0,0><<<dim3(EMBED/128, NCTX/128), blk, 0, stream>>>(
        ctxb, wt_kc, bk_c, nullptr, kbuf, NCTX, EMBED, CROSS);
    gemm_mfma_kernel<0,0><<<dim3(EMBED/128, NCTX/128), blk, 0, stream>>>(
        ctxb, wt_vc, bv_c, nullptr, vbuf, NCTX, EMBED, CROSS);
    flash_attn_kernel<CTX><<<agrid, blk, 0, stream>>>(
        qbuf, kbuf, vbuf, bias_c, obuf, scale);
    gemm_mfma_kernel<0,0><<<dim3(EMBED/128, NTOK/128), blk, 0, stream>>>(
        obuf, wt_oc, bo_c, hidden, hbuf, NTOK, EMBED, EMBED);

    // ---- self attention block ----
    ln_kernel<<<(int)NTOK, blk, 0, stream>>>(hbuf, sn_g, sn_b, xbuf);
    gemm_mfma_kernel<0,0><<<dim3(EMBED/128, NTOK/128), blk, 0, stream>>>(
        xbuf, wt_qs, bq_s, nullptr, qbuf, NTOK, EMBED, EMBED);
    gemm_mfma_kernel<0,0><<<dim3(EMBED/128, NTOK/128), blk, 0, stream>>>(
        xbuf, wt_ks, bk_s, nullptr, kbuf, NTOK, EMBED, EMBED);
    gemm_mfma_kernel<0,0><<<dim3(EMBED/128, NTOK/128), blk, 0, stream>>>(
        xbuf, wt_vs, bv_s, nullptr, vbuf, NTOK, EMBED, EMBED);
    flash_attn_kernel<SEQ><<<agrid, blk, 0, stream>>>(
        qbuf, kbuf, vbuf, bias_s, obuf, scale);
    gemm_mfma_kernel<0,0><<<dim3(EMBED/128, NTOK/128), blk, 0, stream>>>(
        obuf, wt_os, bo_s, hbuf, hbuf, NTOK, EMBED, EMBED);  // in-place resid (1:1)

    // ---- FFN ----
    ln_kernel<<<(int)NTOK, blk, 0, stream>>>(hbuf, fn_g, fn_b, xbuf);
    gemm_mfma_kernel<1,1><<<dim3(FFN_DIM/128, NTOK/128), blk, 0, stream>>>(
        xbuf, wt_w1, b1, nullptr, fbuf, NTOK, FFN_DIM, EMBED);
    gemm_mfma_kernel<0,0><<<dim3(EMBED/128, NTOK/128), blk, 0, stream>>>(
        fbuf, wt_w2, b2, nullptr, out, NTOK, EMBED, FFN_DIM);
}

// Round 6
// 828.158 us; speedup vs baseline: 12.5799x; 1.4117x over previous
//
#include <hip/hip_runtime.h>
#include <hip/hip_bf16.h>
#include <math.h>

#define EMBED 768
#define CROSS 512
#define HEADS 12
#define HDIM  64
#define FFN_DIM 3072
#define BATCH 8
#define SEQ   1024
#define CTX   256
#define LN_EPS 1e-5f

using f32x4 = __attribute__((ext_vector_type(4))) float;
using s16x8 = __attribute__((ext_vector_type(8))) short;   // 8 bf16 in 4 VGPRs

// float -> bf16 (RNE), bit-trick
__device__ __forceinline__ unsigned short f2bf(float f) {
    union { float f; unsigned u; } x{f};
    const unsigned r = x.u + 0x7fffu + ((x.u >> 16) & 1u);
    return (unsigned short)(r >> 16);
}

__device__ __forceinline__ void gl16(const void* g, void* l) {
    __builtin_amdgcn_global_load_lds(
        (const __attribute__((address_space(1))) void*)g,
        (__attribute__((address_space(3))) void*)l, 16, 0, 0);
}

__device__ __forceinline__ float gelu_f(float x) {
    const float c = 0.7978845608028654f;  // sqrt(2/pi)
    return 0.5f * x * (1.0f + tanhf(c * (x + 0.044715f * x * x * x)));
}

// ---------------------------------------------------------------------------
// Weight prep: W[K,N] fp32 -> WT[N,K] bf16 (transposed, K-contiguous)
// ---------------------------------------------------------------------------
__global__ __launch_bounds__(256) void transpose_cast_kernel(
    const float* __restrict__ W, unsigned short* __restrict__ WT, int K, int N)
{
    __shared__ float T[32][33];
    const int k0 = blockIdx.y * 32, n0 = blockIdx.x * 32;
    const int t = threadIdx.x;
    const int r = t >> 3, c4 = (t & 7) * 4;
    const float4 v = *(const float4*)(W + (size_t)(k0 + r) * N + n0 + c4);
    T[r][c4 + 0] = v.x; T[r][c4 + 1] = v.y; T[r][c4 + 2] = v.z; T[r][c4 + 3] = v.w;
    __syncthreads();
    ushort4 o;
    o.x = f2bf(T[c4 + 0][r]); o.y = f2bf(T[c4 + 1][r]);
    o.z = f2bf(T[c4 + 2][r]); o.w = f2bf(T[c4 + 3][r]);
    *(ushort4*)(WT + (size_t)(n0 + r) * K + k0 + c4) = o;
}

// elementwise fp32 -> bf16
__global__ __launch_bounds__(256) void cast_bf16_kernel(
    const float* __restrict__ x, unsigned short* __restrict__ y, int n)
{
    const int i = (blockIdx.x * 256 + threadIdx.x) * 4;
    if (i < n) {
        const float4 v = *(const float4*)(x + i);
        ushort4 o{f2bf(v.x), f2bf(v.y), f2bf(v.z), f2bf(v.w)};
        *(ushort4*)(y + i) = o;
    }
}

// ---------------------------------------------------------------------------
// LayerNorm over 768, writes bf16. One block per row.
// ---------------------------------------------------------------------------
__global__ __launch_bounds__(256) void ln_kernel(
    const float* __restrict__ x, const float* __restrict__ g,
    const float* __restrict__ beta, unsigned short* __restrict__ y)
{
    __shared__ float red[256];
    const size_t row = blockIdx.x;
    const float* xr = x + row * EMBED;
    const int t = threadIdx.x;

    float v0 = xr[t], v1 = xr[t + 256], v2 = xr[t + 512];

    red[t] = v0 + v1 + v2;
    __syncthreads();
    for (int off = 128; off > 0; off >>= 1) {
        if (t < off) red[t] += red[t + off];
        __syncthreads();
    }
    const float mu = red[0] * (1.0f / (float)EMBED);
    __syncthreads();

    const float d0 = v0 - mu, d1 = v1 - mu, d2 = v2 - mu;
    red[t] = d0 * d0 + d1 * d1 + d2 * d2;
    __syncthreads();
    for (int off = 128; off > 0; off >>= 1) {
        if (t < off) red[t] += red[t + off];
        __syncthreads();
    }
    const float var = red[0] * (1.0f / (float)EMBED);
    const float rstd = rsqrtf(var + LN_EPS);

    unsigned short* yr = y + row * EMBED;
    yr[t]       = f2bf(d0 * rstd * g[t]       + beta[t]);
    yr[t + 256] = f2bf(d1 * rstd * g[t + 256] + beta[t + 256]);
    yr[t + 512] = f2bf(d2 * rstd * g[t + 512] + beta[t + 512]);
}

// ---------------------------------------------------------------------------
// bf16 MFMA GEMM, 128x128 tile, BK=32, 4 waves.
// MODE: 0 = f32 out, 1 = bf16 out, 2 = bf16 out transposed per head [b,h,d,k]
// (sklog = log2 of sequence length for MODE 2).
// ---------------------------------------------------------------------------
template <int MODE, int DO_GELU>
__global__ __launch_bounds__(256) void gemm_mfma_kernel(
    const unsigned short* __restrict__ A,   // [M,K]
    const unsigned short* __restrict__ WT,  // [N,K]
    const float* __restrict__ bias,         // [N]
    const float* __restrict__ resid,        // [M,N] or null
    void* __restrict__ Cv, int M, int N, int K, int sklog)
{
    __shared__ unsigned short As[128][32];
    __shared__ unsigned short Bs[128][32];

    const int t = threadIdx.x;
    const int l = t & 63;
    const int w = t >> 6;
    const int m0 = blockIdx.y * 128;
    const int n0 = blockIdx.x * 128;
    const int wm = (w >> 1) * 64;
    const int wn = (w & 1) * 64;

    const int sr = t >> 2;
    const int sc = t & 3;

    f32x4 acc[4][4] = {};

    const unsigned short* Ap0 = A  + (size_t)(m0 + sr) * K + sc * 8;
    const unsigned short* Ap1 = Ap0 + (size_t)64 * K;
    const unsigned short* Bp0 = WT + (size_t)(n0 + sr) * K + sc * 8;
    const unsigned short* Bp1 = Bp0 + (size_t)64 * K;

    const int fr = l & 15;
    const int kb = (l >> 4) * 8;

    for (int k0 = 0; k0 < K; k0 += 32) {
        gl16(Ap0 + k0, &As[sr][sc * 8]);
        gl16(Ap1 + k0, &As[sr + 64][sc * 8]);
        gl16(Bp0 + k0, &Bs[sr][sc * 8]);
        gl16(Bp1 + k0, &Bs[sr + 64][sc * 8]);
        __syncthreads();

        s16x8 af[4], bf[4];
#pragma unroll
        for (int i = 0; i < 4; ++i) af[i] = *(const s16x8*)&As[wm + i * 16 + fr][kb];
#pragma unroll
        for (int j = 0; j < 4; ++j) bf[j] = *(const s16x8*)&Bs[wn + j * 16 + fr][kb];
#pragma unroll
        for (int i = 0; i < 4; ++i)
#pragma unroll
            for (int j = 0; j < 4; ++j)
                acc[i][j] = __builtin_amdgcn_mfma_f32_16x16x32_bf16(
                    af[i], bf[j], acc[i][j], 0, 0, 0);
        __syncthreads();
    }

    const int rg = (l >> 4) * 4;
#pragma unroll
    for (int j = 0; j < 4; ++j) {
        const int col = n0 + wn + j * 16 + fr;
        const float bia = bias[col];
#pragma unroll
        for (int i = 0; i < 4; ++i) {
#pragma unroll
            for (int r = 0; r < 4; ++r) {
                const int row = m0 + wm + i * 16 + rg + r;
                float v = acc[i][j][r] + bia;
                if (resid) v += resid[(size_t)row * N + col];
                if (DO_GELU) v = gelu_f(v);
                if (MODE == 0) {
                    ((float*)Cv)[(size_t)row * N + col] = v;
                } else if (MODE == 1) {
                    ((unsigned short*)Cv)[(size_t)row * N + col] = f2bf(v);
                } else {
                    const int bb = row >> sklog;
                    const int kk = row - (bb << sklog);
                    const int hh = col >> 6;
                    const int dd = col & 63;
                    ((unsigned short*)Cv)[
                        (((size_t)(bb * HEADS + hh) * 64 + dd) << sklog) + kk] = f2bf(v);
                }
            }
        }
    }
}

// ---------------------------------------------------------------------------
// MFMA flash attention. Block = 64 q-rows of one (b,h); 4 waves x 16 q-rows.
// Q,K: [B*T, 768] bf16 (head slice at h*64). VT: [B,H,64,SK] bf16.
// bias: [H, SEQ, SK] f32. O: [B*SEQ, 768] bf16.
// LDS tiles [64][72] padded (frag reads 2-way = free). P is wave-local.
// XCD-bijective swizzle: logical order b-fastest so the 8 blocks sharing a
// bias slab co-reside on one XCD (L2 reuse).
// ---------------------------------------------------------------------------
template <int SK>
__global__ __launch_bounds__(256) void flash_mfma_kernel(
    const unsigned short* __restrict__ Q, const unsigned short* __restrict__ K,
    const unsigned short* __restrict__ VT, const float* __restrict__ bias,
    unsigned short* __restrict__ O, float scale)
{
    __shared__ unsigned short Qs[64][72];
    __shared__ unsigned short Ks[64][72];
    __shared__ unsigned short Vts[64][72];
    __shared__ unsigned short Ps[64][72];

    // nwg = 8*16*12 = 1536; chunk = 192 per XCD
    const int g = blockIdx.x;
    const int L = (g & 7) * 192 + (g >> 3);
    const int b  = L & 7;
    const int qt = (L >> 3) & 15;
    const int h  = L >> 7;
    const int q0 = qt * 64;

    const int t  = threadIdx.x;
    const int l  = t & 63;
    const int w  = t >> 6;
    const int fr = l & 15;
    const int hi = l >> 4;

    const int str = t >> 3;        // staging row 0..31 (+32 second pass)
    const int stc = (t & 7) * 8;   // staging col (elements)

    // ---- stage Q (2 passes) ----
#pragma unroll
    for (int ps = 0; ps < 2; ++ps) {
        const int r = str + ps * 32;
        *(uint4*)&Qs[r][stc] =
            *(const uint4*)(Q + ((size_t)(b * SEQ) + q0 + r) * EMBED + h * HDIM + stc);
    }

    float m_[4], l_[4];
    f32x4 o_[4];
#pragma unroll
    for (int r = 0; r < 4; ++r) { m_[r] = -1e30f; l_[r] = 0.0f; }
#pragma unroll
    for (int n = 0; n < 4; ++n) o_[n] = f32x4{0.f, 0.f, 0.f, 0.f};

    const float* bbase = bias + ((size_t)h * SEQ + q0 + w * 16) * SK;

    for (int k0 = 0; k0 < SK; k0 += 64) {
        // ---- stage K and V^T tiles ----
#pragma unroll
        for (int ps = 0; ps < 2; ++ps) {
            const int r = str + ps * 32;
            *(uint4*)&Ks[r][stc] =
                *(const uint4*)(K + ((size_t)(b * SK) + k0 + r) * EMBED + h * HDIM + stc);
            *(uint4*)&Vts[r][stc] =
                *(const uint4*)(VT + ((size_t)(b * HEADS + h) * 64 + r) * SK + k0 + stc);
        }
        __syncthreads();

        // ---- QK^T: S[16q x 64k] per wave ----
        f32x4 s[4] = {};
#pragma unroll
        for (int ks = 0; ks < 2; ++ks) {
            const s16x8 aq = *(const s16x8*)&Qs[w * 16 + fr][ks * 32 + hi * 8];
#pragma unroll
            for (int j = 0; j < 4; ++j) {
                const s16x8 bk = *(const s16x8*)&Ks[j * 16 + fr][ks * 32 + hi * 8];
                s[j] = __builtin_amdgcn_mfma_f32_16x16x32_bf16(aq, bk, s[j], 0, 0, 0);
            }
        }

        // ---- online softmax; rows = hi*4 + r, cols = fr + 16j ----
        float corr[4];
#pragma unroll
        for (int r = 0; r < 4; ++r) {
            const float* br = bbase + (size_t)(hi * 4 + r) * SK + k0 + fr;
            float v0 = s[0][r] * scale + br[0];
            float v1 = s[1][r] * scale + br[16];
            float v2 = s[2][r] * scale + br[32];
            float v3 = s[3][r] * scale + br[48];
            float mx = fmaxf(fmaxf(v0, v1), fmaxf(v2, v3));
            mx = fmaxf(mx, __shfl_xor(mx, 1));
            mx = fmaxf(mx, __shfl_xor(mx, 2));
            mx = fmaxf(mx, __shfl_xor(mx, 4));
            mx = fmaxf(mx, __shfl_xor(mx, 8));
            const float mnew = fmaxf(m_[r], mx);
            const float c = __expf(m_[r] - mnew);
            m_[r] = mnew;
            const float p0 = __expf(v0 - mnew);
            const float p1 = __expf(v1 - mnew);
            const float p2 = __expf(v2 - mnew);
            const float p3 = __expf(v3 - mnew);
            float psum = p0 + p1 + p2 + p3;
            psum += __shfl_xor(psum, 1);
            psum += __shfl_xor(psum, 2);
            psum += __shfl_xor(psum, 4);
            psum += __shfl_xor(psum, 8);
            l_[r] = l_[r] * c + psum;
            corr[r] = c;
            const int prow = w * 16 + hi * 4 + r;
            Ps[prow][fr]      = f2bf(p0);
            Ps[prow][fr + 16] = f2bf(p1);
            Ps[prow][fr + 32] = f2bf(p2);
            Ps[prow][fr + 48] = f2bf(p3);
        }
#pragma unroll
        for (int n = 0; n < 4; ++n)
#pragma unroll
            for (int r = 0; r < 4; ++r) o_[n][r] *= corr[r];

        // ---- PV: O[16q x 64d] per wave (P is wave-local; no barrier) ----
#pragma unroll
        for (int ks = 0; ks < 2; ++ks) {
            const s16x8 ap = *(const s16x8*)&Ps[w * 16 + fr][ks * 32 + hi * 8];
#pragma unroll
            for (int n = 0; n < 4; ++n) {
                const s16x8 bv = *(const s16x8*)&Vts[n * 16 + fr][ks * 32 + hi * 8];
                o_[n] = __builtin_amdgcn_mfma_f32_16x16x32_bf16(ap, bv, o_[n], 0, 0, 0);
            }
        }
        __syncthreads();   // tile reads done before next staging
    }

    // ---- finalize + store (rows hi*4+r, cols fr+16n) ----
    float inv[4];
#pragma unroll
    for (int r = 0; r < 4; ++r) inv[r] = 1.0f / l_[r];
#pragma unroll
    for (int n = 0; n < 4; ++n)
#pragma unroll
        for (int r = 0; r < 4; ++r)
            O[((size_t)(b * SEQ) + q0 + w * 16 + hi * 4 + r) * EMBED +
              h * HDIM + n * 16 + fr] = f2bf(o_[n][r] * inv[r]);
}

// ---------------------------------------------------------------------------
// Launch
// ---------------------------------------------------------------------------
extern "C" void kernel_launch(void* const* d_in, const int* in_sizes, int n_in,
                              void* d_out, int out_size, void* d_ws, size_t ws_size,
                              hipStream_t stream)
{
    const float* hidden  = (const float*)d_in[0];
    const float* context = (const float*)d_in[1];
    const float* cn_g = (const float*)d_in[2];
    const float* cn_b = (const float*)d_in[3];
    const float* wq_c = (const float*)d_in[4];
    const float* bq_c = (const float*)d_in[5];
    const float* wk_c = (const float*)d_in[6];
    const float* bk_c = (const float*)d_in[7];
    const float* wv_c = (const float*)d_in[8];
    const float* bv_c = (const float*)d_in[9];
    const float* wo_c = (const float*)d_in[10];
    const float* bo_c = (const float*)d_in[11];
    const float* bias_c = (const float*)d_in[12];
    const float* sn_g = (const float*)d_in[13];
    const float* sn_b = (const float*)d_in[14];
    const float* wq_s = (const float*)d_in[15];
    const float* bq_s = (const float*)d_in[16];
    const float* wk_s = (const float*)d_in[17];
    const float* bk_s = (const float*)d_in[18];
    const float* wv_s = (const float*)d_in[19];
    const float* bv_s = (const float*)d_in[20];
    const float* wo_s = (const float*)d_in[21];
    const float* bo_s = (const float*)d_in[22];
    const float* bias_s = (const float*)d_in[23];
    const float* fn_g = (const float*)d_in[24];
    const float* fn_b = (const float*)d_in[25];
    const float* w1 = (const float*)d_in[26];
    const float* b1 = (const float*)d_in[27];
    const float* w2 = (const float*)d_in[28];
    const float* b2 = (const float*)d_in[29];

    const size_t NTOK = (size_t)BATCH * SEQ;   // 8192
    const size_t NCTX = (size_t)BATCH * CTX;   // 2048
    const size_t TE = NTOK * EMBED;            // 6291456

    // ---- workspace layout (qbuf..obuf contiguous; fbuf aliases that span) ----
    char* p = (char*)d_ws;
    float* hbuf = (float*)p;                   p += TE * 4;
    unsigned short* xbuf = (unsigned short*)p; p += TE * 2;
    unsigned short* qbuf = (unsigned short*)p; p += TE * 2;
    unsigned short* kbuf = (unsigned short*)p; p += TE * 2;
    unsigned short* vbuf = (unsigned short*)p; p += TE * 2;
    unsigned short* obuf = (unsigned short*)p; p += TE * 2;
    unsigned short* ctxb = (unsigned short*)p; p += NCTX * CROSS * 2;
    unsigned short* wt_qc = (unsigned short*)p; p += (size_t)EMBED * EMBED * 2;
    unsigned short* wt_kc = (unsigned short*)p; p += (size_t)CROSS * EMBED * 2;
    unsigned short* wt_vc = (unsigned short*)p; p += (size_t)CROSS * EMBED * 2;
    unsigned short* wt_oc = (unsigned short*)p; p += (size_t)EMBED * EMBED * 2;
    unsigned short* wt_qs = (unsigned short*)p; p += (size_t)EMBED * EMBED * 2;
    unsigned short* wt_ks = (unsigned short*)p; p += (size_t)EMBED * EMBED * 2;
    unsigned short* wt_vs = (unsigned short*)p; p += (size_t)EMBED * EMBED * 2;
    unsigned short* wt_os = (unsigned short*)p; p += (size_t)EMBED * EMBED * 2;
    unsigned short* wt_w1 = (unsigned short*)p; p += (size_t)EMBED * FFN_DIM * 2;
    unsigned short* wt_w2 = (unsigned short*)p; p += (size_t)FFN_DIM * EMBED * 2;
    unsigned short* fbuf = qbuf;   // [8192,3072] bf16 = q+k+v+o span exactly
    float* out = (float*)d_out;

    const dim3 blk(256);
    const float scale = 0.125f;
    const dim3 agrid(BATCH * (SEQ / 64) * HEADS);   // 1536

    // ---- weight prep ----
    transpose_cast_kernel<<<dim3(EMBED/32, EMBED/32), blk, 0, stream>>>(wq_c, wt_qc, EMBED, EMBED);
    transpose_cast_kernel<<<dim3(EMBED/32, CROSS/32), blk, 0, stream>>>(wk_c, wt_kc, CROSS, EMBED);
    transpose_cast_kernel<<<dim3(EMBED/32, CROSS/32), blk, 0, stream>>>(wv_c, wt_vc, CROSS, EMBED);
    transpose_cast_kernel<<<dim3(EMBED/32, EMBED/32), blk, 0, stream>>>(wo_c, wt_oc, EMBED, EMBED);
    transpose_cast_kernel<<<dim3(EMBED/32, EMBED/32), blk, 0, stream>>>(wq_s, wt_qs, EMBED, EMBED);
    transpose_cast_kernel<<<dim3(EMBED/32, EMBED/32), blk, 0, stream>>>(wk_s, wt_ks, EMBED, EMBED);
    transpose_cast_kernel<<<dim3(EMBED/32, EMBED/32), blk, 0, stream>>>(wv_s, wt_vs, EMBED, EMBED);
    transpose_cast_kernel<<<dim3(EMBED/32, EMBED/32), blk, 0, stream>>>(wo_s, wt_os, EMBED, EMBED);
    transpose_cast_kernel<<<dim3(FFN_DIM/32, EMBED/32), blk, 0, stream>>>(w1, wt_w1, EMBED, FFN_DIM);
    transpose_cast_kernel<<<dim3(EMBED/32, FFN_DIM/32), blk, 0, stream>>>(w2, wt_w2, FFN_DIM, EMBED);
    cast_bf16_kernel<<<(int)(NCTX * CROSS / 1024), blk, 0, stream>>>(
        context, ctxb, (int)(NCTX * CROSS));

    // ---- cross attention block ----
    ln_kernel<<<(int)NTOK, blk, 0, stream>>>(hidden, cn_g, cn_b, xbuf);
    gemm_mfma_kernel<1,0><<<dim3(EMBED/128, NTOK/128), blk, 0, stream>>>(
        xbuf, wt_qc, bq_c, nullptr, qbuf, NTOK, EMBED, EMBED, 0);
    gemm_mfma_kernel<1,0><<<dim3(EMBED/128, NCTX/128), blk, 0, stream>>>(
        ctxb, wt_kc, bk_c, nullptr, kbuf, NCTX, EMBED, CROSS, 0);
    gemm_mfma_kernel<2,0><<<dim3(EMBED/128, NCTX/128), blk, 0, stream>>>(
        ctxb, wt_vc, bv_c, nullptr, vbuf, NCTX, EMBED, CROSS, 8);   // V^T, sk=256
    flash_mfma_kernel<CTX><<<agrid, blk, 0, stream>>>(
        qbuf, kbuf, vbuf, bias_c, obuf, scale);
    gemm_mfma_kernel<0,0><<<dim3(EMBED/128, NTOK/128), blk, 0, stream>>>(
        obuf, wt_oc, bo_c, hidden, hbuf, NTOK, EMBED, EMBED, 0);

    // ---- self attention block ----
    ln_kernel<<<(int)NTOK, blk, 0, stream>>>(hbuf, sn_g, sn_b, xbuf);
    gemm_mfma_kernel<1,0><<<dim3(EMBED/128, NTOK/128), blk, 0, stream>>>(
        xbuf, wt_qs, bq_s, nullptr, qbuf, NTOK, EMBED, EMBED, 0);
    gemm_mfma_kernel<1,0><<<dim3(EMBED/128, NTOK/128), blk, 0, stream>>>(
        xbuf, wt_ks, bk_s, nullptr, kbuf, NTOK, EMBED, EMBED, 0);
    gemm_mfma_kernel<2,0><<<dim3(EMBED/128, NTOK/128), blk, 0, stream>>>(
        xbuf, wt_vs, bv_s, nullptr, vbuf, NTOK, EMBED, EMBED, 10);  // V^T, sk=1024
    flash_mfma_kernel<SEQ><<<agrid, blk, 0, stream>>>(
        qbuf, kbuf, vbuf, bias_s, obuf, scale);
    gemm_mfma_kernel<0,0><<<dim3(EMBED/128, NTOK/128), blk, 0, stream>>>(
        obuf, wt_os, bo_s, hbuf, hbuf, NTOK, EMBED, EMBED, 0);  // in-place resid

    // ---- FFN ----
    ln_kernel<<<(int)NTOK, blk, 0, stream>>>(hbuf, fn_g, fn_b, xbuf);
    gemm_mfma_kernel<1,1><<<dim3(FFN_DIM/128, NTOK/128), blk, 0, stream>>>(
        xbuf, wt_w1, b1, nullptr, fbuf, NTOK, FFN_DIM, EMBED, 0);
    gemm_mfma_kernel<0,0><<<dim3(EMBED/128, NTOK/128), blk, 0, stream>>>(
        fbuf, wt_w2, b2, nullptr, out, NTOK, EMBED, FFN_DIM, 0);
}

// Round 11
// 812.039 us; speedup vs baseline: 12.8296x; 1.0199x over previous
//
#include <hip/hip_runtime.h>
#include <hip/hip_bf16.h>
#include <math.h>

#define EMBED 768
#define CROSS 512
#define HEADS 12
#define HDIM  64
#define FFN_DIM 3072
#define BATCH 8
#define SEQ   1024
#define CTX   256
#define LN_EPS 1e-5f

using f32x4 = __attribute__((ext_vector_type(4))) float;
using s16x8 = __attribute__((ext_vector_type(8))) short;   // 8 bf16 in 4 VGPRs

// float -> bf16 (RNE), bit-trick
__device__ __forceinline__ unsigned short f2bf(float f) {
    union { float f; unsigned u; } x{f};
    const unsigned r = x.u + 0x7fffu + ((x.u >> 16) & 1u);
    return (unsigned short)(r >> 16);
}

__device__ __forceinline__ void gl16(const void* g, void* l) {
    __builtin_amdgcn_global_load_lds(
        (const __attribute__((address_space(1))) void*)g,
        (__attribute__((address_space(3))) void*)l, 16, 0, 0);
}

__device__ __forceinline__ float gelu_f(float x) {
    const float c = 0.7978845608028654f;  // sqrt(2/pi)
    return 0.5f * x * (1.0f + tanhf(c * (x + 0.044715f * x * x * x)));
}

// ---------------------------------------------------------------------------
// Weight prep: W[K,N] fp32 -> WT[N,K] bf16 (transposed, K-contiguous)
// ---------------------------------------------------------------------------
__global__ __launch_bounds__(256) void transpose_cast_kernel(
    const float* __restrict__ W, unsigned short* __restrict__ WT, int K, int N)
{
    __shared__ float T[32][33];
    const int k0 = blockIdx.y * 32, n0 = blockIdx.x * 32;
    const int t = threadIdx.x;
    const int r = t >> 3, c4 = (t & 7) * 4;
    const float4 v = *(const float4*)(W + (size_t)(k0 + r) * N + n0 + c4);
    T[r][c4 + 0] = v.x; T[r][c4 + 1] = v.y; T[r][c4 + 2] = v.z; T[r][c4 + 3] = v.w;
    __syncthreads();
    ushort4 o;
    o.x = f2bf(T[c4 + 0][r]); o.y = f2bf(T[c4 + 1][r]);
    o.z = f2bf(T[c4 + 2][r]); o.w = f2bf(T[c4 + 3][r]);
    *(ushort4*)(WT + (size_t)(n0 + r) * K + k0 + c4) = o;
}

// elementwise fp32 -> bf16
__global__ __launch_bounds__(256) void cast_bf16_kernel(
    const float* __restrict__ x, unsigned short* __restrict__ y, int n)
{
    const int i = (blockIdx.x * 256 + threadIdx.x) * 4;
    if (i < n) {
        const float4 v = *(const float4*)(x + i);
        ushort4 o{f2bf(v.x), f2bf(v.y), f2bf(v.z), f2bf(v.w)};
        *(ushort4*)(y + i) = o;
    }
}

// ---------------------------------------------------------------------------
// LayerNorm over 768, writes bf16. One block per row.
// ---------------------------------------------------------------------------
__global__ __launch_bounds__(256) void ln_kernel(
    const float* __restrict__ x, const float* __restrict__ g,
    const float* __restrict__ beta, unsigned short* __restrict__ y)
{
    __shared__ float red[256];
    const size_t row = blockIdx.x;
    const float* xr = x + row * EMBED;
    const int t = threadIdx.x;

    float v0 = xr[t], v1 = xr[t + 256], v2 = xr[t + 512];

    red[t] = v0 + v1 + v2;
    __syncthreads();
    for (int off = 128; off > 0; off >>= 1) {
        if (t < off) red[t] += red[t + off];
        __syncthreads();
    }
    const float mu = red[0] * (1.0f / (float)EMBED);
    __syncthreads();

    const float d0 = v0 - mu, d1 = v1 - mu, d2 = v2 - mu;
    red[t] = d0 * d0 + d1 * d1 + d2 * d2;
    __syncthreads();
    for (int off = 128; off > 0; off >>= 1) {
        if (t < off) red[t] += red[t + off];
        __syncthreads();
    }
    const float var = red[0] * (1.0f / (float)EMBED);
    const float rstd = rsqrtf(var + LN_EPS);

    unsigned short* yr = y + row * EMBED;
    yr[t]       = f2bf(d0 * rstd * g[t]       + beta[t]);
    yr[t + 256] = f2bf(d1 * rstd * g[t + 256] + beta[t + 256]);
    yr[t + 512] = f2bf(d2 * rstd * g[t + 512] + beta[t + 512]);
}

// ---------------------------------------------------------------------------
// bf16 MFMA GEMM, 128x128 tile, BK=32, 4 waves.
// MODE: 0 = f32 out, 1 = bf16 out.
// ---------------------------------------------------------------------------
template <int MODE, int DO_GELU>
__global__ __launch_bounds__(256) void gemm_mfma_kernel(
    const unsigned short* __restrict__ A,   // [M,K]
    const unsigned short* __restrict__ WT,  // [N,K]
    const float* __restrict__ bias,         // [N]
    const float* __restrict__ resid,        // [M,N] or null
    void* __restrict__ Cv, int M, int N, int K)
{
    __shared__ unsigned short As[128][32];
    __shared__ unsigned short Bs[128][32];

    const int t = threadIdx.x;
    const int l = t & 63;
    const int w = t >> 6;
    const int m0 = blockIdx.y * 128;
    const int n0 = blockIdx.x * 128;
    const int wm = (w >> 1) * 64;
    const int wn = (w & 1) * 64;

    const int sr = t >> 2;
    const int sc = t & 3;

    f32x4 acc[4][4] = {};

    const unsigned short* Ap0 = A  + (size_t)(m0 + sr) * K + sc * 8;
    const unsigned short* Ap1 = Ap0 + (size_t)64 * K;
    const unsigned short* Bp0 = WT + (size_t)(n0 + sr) * K + sc * 8;
    const unsigned short* Bp1 = Bp0 + (size_t)64 * K;

    const int fr = l & 15;
    const int kb = (l >> 4) * 8;

    for (int k0 = 0; k0 < K; k0 += 32) {
        gl16(Ap0 + k0, &As[sr][sc * 8]);
        gl16(Ap1 + k0, &As[sr + 64][sc * 8]);
        gl16(Bp0 + k0, &Bs[sr][sc * 8]);
        gl16(Bp1 + k0, &Bs[sr + 64][sc * 8]);
        __syncthreads();

        s16x8 af[4], bf[4];
#pragma unroll
        for (int i = 0; i < 4; ++i) af[i] = *(const s16x8*)&As[wm + i * 16 + fr][kb];
#pragma unroll
        for (int j = 0; j < 4; ++j) bf[j] = *(const s16x8*)&Bs[wn + j * 16 + fr][kb];
#pragma unroll
        for (int i = 0; i < 4; ++i)
#pragma unroll
            for (int j = 0; j < 4; ++j)
                acc[i][j] = __builtin_amdgcn_mfma_f32_16x16x32_bf16(
                    af[i], bf[j], acc[i][j], 0, 0, 0);
        __syncthreads();
    }

    const int rg = (l >> 4) * 4;
#pragma unroll
    for (int j = 0; j < 4; ++j) {
        const int col = n0 + wn + j * 16 + fr;
        const float bia = bias[col];
#pragma unroll
        for (int i = 0; i < 4; ++i) {
#pragma unroll
            for (int r = 0; r < 4; ++r) {
                const int row = m0 + wm + i * 16 + rg + r;
                float v = acc[i][j][r] + bia;
                if (resid) v += resid[(size_t)row * N + col];
                if (DO_GELU) v = gelu_f(v);
                if (MODE == 0) {
                    ((float*)Cv)[(size_t)row * N + col] = v;
                } else {
                    ((unsigned short*)Cv)[(size_t)row * N + col] = f2bf(v);
                }
            }
        }
    }
}

// ---------------------------------------------------------------------------
// Fused projection GEMM over concatenated weights WT[Ntot,K] (Ntot = 768*P).
// 768 % 128 == 0, so each 128-col block lies in exactly one part.
// part == vpart -> write V^T per head [b,h,d,k] (sklog = log2 seq len);
// else bf16 [M,768] to out0/out1. Bias selected per part (b0,b1,b2).
// ---------------------------------------------------------------------------
__global__ __launch_bounds__(256) void gemm_qkv_kernel(
    const unsigned short* __restrict__ A,   // [M,K]
    const unsigned short* __restrict__ WT,  // [Ntot,K] concat
    const float* __restrict__ b0, const float* __restrict__ b1,
    const float* __restrict__ b2,
    unsigned short* __restrict__ out0, unsigned short* __restrict__ out1,
    unsigned short* __restrict__ vt,
    int M, int K, int sklog, int vpart)
{
    __shared__ unsigned short As[128][32];
    __shared__ unsigned short Bs[128][32];

    const int t = threadIdx.x;
    const int l = t & 63;
    const int w = t >> 6;
    const int m0 = blockIdx.y * 128;
    const int n0 = blockIdx.x * 128;
    const int part = n0 / 768;
    const int nl0 = n0 - part * 768;
    const float* bias = (part == 0) ? b0 : ((part == 1) ? b1 : b2);
    const int wm = (w >> 1) * 64;
    const int wn = (w & 1) * 64;

    const int sr = t >> 2;
    const int sc = t & 3;

    f32x4 acc[4][4] = {};

    const unsigned short* Ap0 = A  + (size_t)(m0 + sr) * K + sc * 8;
    const unsigned short* Ap1 = Ap0 + (size_t)64 * K;
    const unsigned short* Bp0 = WT + (size_t)(n0 + sr) * K + sc * 8;
    const unsigned short* Bp1 = Bp0 + (size_t)64 * K;

    const int fr = l & 15;
    const int kb = (l >> 4) * 8;

    for (int k0 = 0; k0 < K; k0 += 32) {
        gl16(Ap0 + k0, &As[sr][sc * 8]);
        gl16(Ap1 + k0, &As[sr + 64][sc * 8]);
        gl16(Bp0 + k0, &Bs[sr][sc * 8]);
        gl16(Bp1 + k0, &Bs[sr + 64][sc * 8]);
        __syncthreads();

        s16x8 af[4], bf[4];
#pragma unroll
        for (int i = 0; i < 4; ++i) af[i] = *(const s16x8*)&As[wm + i * 16 + fr][kb];
#pragma unroll
        for (int j = 0; j < 4; ++j) bf[j] = *(const s16x8*)&Bs[wn + j * 16 + fr][kb];
#pragma unroll
        for (int i = 0; i < 4; ++i)
#pragma unroll
            for (int j = 0; j < 4; ++j)
                acc[i][j] = __builtin_amdgcn_mfma_f32_16x16x32_bf16(
                    af[i], bf[j], acc[i][j], 0, 0, 0);
        __syncthreads();
    }

    const int rg = (l >> 4) * 4;
    unsigned short* outp = (part == 0) ? out0 : out1;
#pragma unroll
    for (int j = 0; j < 4; ++j) {
        const int nl = nl0 + wn + j * 16 + fr;
        const float bia = bias[nl];
#pragma unroll
        for (int i = 0; i < 4; ++i) {
#pragma unroll
            for (int r = 0; r < 4; ++r) {
                const int row = m0 + wm + i * 16 + rg + r;
                const float v = acc[i][j][r] + bia;
                if (part == vpart) {
                    const int bb = row >> sklog;
                    const int kk = row - (bb << sklog);
                    const int hh = nl >> 6;
                    const int dd = nl & 63;
                    vt[(((size_t)(bb * HEADS + hh) * 64 + dd) << sklog) + kk] = f2bf(v);
                } else {
                    outp[(size_t)row * 768 + nl] = f2bf(v);
                }
            }
        }
    }
}

// ---------------------------------------------------------------------------
// MFMA flash attention with T14 async-stage split.
// Block = 64 q-rows of one (b,h); 4 waves x 16 q-rows.
// Next K/V tile loaded to registers DURING compute, written to LDS after the
// closing barrier; bias prefetched before the QK MFMAs.
// ---------------------------------------------------------------------------
template <int SK>
__global__ __launch_bounds__(256) void flash_mfma_kernel(
    const unsigned short* __restrict__ Q, const unsigned short* __restrict__ K,
    const unsigned short* __restrict__ VT, const float* __restrict__ bias,
    unsigned short* __restrict__ O, float scale)
{
    __shared__ unsigned short Qs[64][72];
    __shared__ unsigned short Ks[64][72];
    __shared__ unsigned short Vts[64][72];
    __shared__ unsigned short Ps[64][72];

    // nwg = 8*16*12 = 1536; 192 per XCD, batch-fastest logical order
    const int g = blockIdx.x;
    const int L = (g & 7) * 192 + (g >> 3);
    const int b  = L & 7;
    const int qt = (L >> 3) & 15;
    const int h  = L >> 7;
    const int q0 = qt * 64;

    const int t  = threadIdx.x;
    const int l  = t & 63;
    const int w  = t >> 6;
    const int fr = l & 15;
    const int hi = l >> 4;

    const int str = t >> 3;        // staging row 0..31 (+32 second pass)
    const int stc = (t & 7) * 8;   // staging col (elements)

    const unsigned short* Kbase = K + (size_t)(b * SK) * EMBED + h * HDIM + stc;

    // ---- stage Q ----
#pragma unroll
    for (int ps = 0; ps < 2; ++ps) {
        const int r = str + ps * 32;
        *(uint4*)&Qs[r][stc] =
            *(const uint4*)(Q + ((size_t)(b * SEQ) + q0 + r) * EMBED + h * HDIM + stc);
    }

    // ---- prologue: tile 0 to regs, then LDS ----
    uint4 kreg[2], vreg[2];
#pragma unroll
    for (int ps = 0; ps < 2; ++ps) {
        const int r = str + ps * 32;
        kreg[ps] = *(const uint4*)(Kbase + (size_t)r * EMBED);
        vreg[ps] = *(const uint4*)(VT + ((size_t)(b * HEADS + h) * 64 + r) * SK + stc);
    }
#pragma unroll
    for (int ps = 0; ps < 2; ++ps) {
        const int r = str + ps * 32;
        *(uint4*)&Ks[r][stc]  = kreg[ps];
        *(uint4*)&Vts[r][stc] = vreg[ps];
    }

    float m_[4], l_[4];
    f32x4 o_[4];
#pragma unroll
    for (int r = 0; r < 4; ++r) { m_[r] = -1e30f; l_[r] = 0.0f; }
#pragma unroll
    for (int n = 0; n < 4; ++n) o_[n] = f32x4{0.f, 0.f, 0.f, 0.f};

    const float* bbase = bias + ((size_t)h * SEQ + q0 + w * 16) * SK;
    __syncthreads();

    for (int k0 = 0; k0 < SK; k0 += 64) {
        const int kn = k0 + 64;
        // ---- issue NEXT-tile loads into registers (T14 issue-early) ----
        if (kn < SK) {
#pragma unroll
            for (int ps = 0; ps < 2; ++ps) {
                const int r = str + ps * 32;
                kreg[ps] = *(const uint4*)(Kbase + (size_t)(kn + r) * EMBED);
                vreg[ps] = *(const uint4*)(VT + ((size_t)(b * HEADS + h) * 64 + r) * SK + kn + stc);
            }
        }

        // ---- bias prefetch for CURRENT tile ----
        float bre[4][4];
#pragma unroll
        for (int r = 0; r < 4; ++r)
#pragma unroll
            for (int j = 0; j < 4; ++j)
                bre[r][j] = bbase[(size_t)(hi * 4 + r) * SK + k0 + fr + 16 * j];

        // ---- QK^T: S[16q x 64k] per wave ----
        f32x4 s[4] = {};
#pragma unroll
        for (int ks = 0; ks < 2; ++ks) {
            const s16x8 aq = *(const s16x8*)&Qs[w * 16 + fr][ks * 32 + hi * 8];
#pragma unroll
            for (int j = 0; j < 4; ++j) {
                const s16x8 bk = *(const s16x8*)&Ks[j * 16 + fr][ks * 32 + hi * 8];
                s[j] = __builtin_amdgcn_mfma_f32_16x16x32_bf16(aq, bk, s[j], 0, 0, 0);
            }
        }

        // ---- online softmax; rows = hi*4 + r, cols = fr + 16j ----
        float corr[4];
#pragma unroll
        for (int r = 0; r < 4; ++r) {
            float v0 = s[0][r] * scale + bre[r][0];
            float v1 = s[1][r] * scale + bre[r][1];
            float v2 = s[2][r] * scale + bre[r][2];
            float v3 = s[3][r] * scale + bre[r][3];
            float mx = fmaxf(fmaxf(v0, v1), fmaxf(v2, v3));
            mx = fmaxf(mx, __shfl_xor(mx, 1));
            mx = fmaxf(mx, __shfl_xor(mx, 2));
            mx = fmaxf(mx, __shfl_xor(mx, 4));
            mx = fmaxf(mx, __shfl_xor(mx, 8));
            const float mnew = fmaxf(m_[r], mx);
            const float c = __expf(m_[r] - mnew);
            m_[r] = mnew;
            const float p0 = __expf(v0 - mnew);
            const float p1 = __expf(v1 - mnew);
            const float p2 = __expf(v2 - mnew);
            const float p3 = __expf(v3 - mnew);
            float psum = p0 + p1 + p2 + p3;
            psum += __shfl_xor(psum, 1);
            psum += __shfl_xor(psum, 2);
            psum += __shfl_xor(psum, 4);
            psum += __shfl_xor(psum, 8);
            l_[r] = l_[r] * c + psum;
            corr[r] = c;
            const int prow = w * 16 + hi * 4 + r;
            Ps[prow][fr]      = f2bf(p0);
            Ps[prow][fr + 16] = f2bf(p1);
            Ps[prow][fr + 32] = f2bf(p2);
            Ps[prow][fr + 48] = f2bf(p3);
        }
#pragma unroll
        for (int n = 0; n < 4; ++n)
#pragma unroll
            for (int r = 0; r < 4; ++r) o_[n][r] *= corr[r];

        // ---- PV: O[16q x 64d] per wave (P wave-local) ----
#pragma unroll
        for (int ks = 0; ks < 2; ++ks) {
            const s16x8 ap = *(const s16x8*)&Ps[w * 16 + fr][ks * 32 + hi * 8];
#pragma unroll
            for (int n = 0; n < 4; ++n) {
                const s16x8 bv = *(const s16x8*)&Vts[n * 16 + fr][ks * 32 + hi * 8];
                o_[n] = __builtin_amdgcn_mfma_f32_16x16x32_bf16(ap, bv, o_[n], 0, 0, 0);
            }
        }
        __syncthreads();   // all reads of Ks/Vts done

        // ---- write NEXT tile regs -> LDS (T14 write-late) ----
        if (kn < SK) {
#pragma unroll
            for (int ps = 0; ps < 2; ++ps) {
                const int r = str + ps * 32;
                *(uint4*)&Ks[r][stc]  = kreg[ps];
                *(uint4*)&Vts[r][stc] = vreg[ps];
            }
            __syncthreads();
        }
    }

    // ---- finalize + store (rows hi*4+r, cols fr+16n) ----
    float inv[4];
#pragma unroll
    for (int r = 0; r < 4; ++r) inv[r] = 1.0f / l_[r];
#pragma unroll
    for (int n = 0; n < 4; ++n)
#pragma unroll
        for (int r = 0; r < 4; ++r)
            O[((size_t)(b * SEQ) + q0 + w * 16 + hi * 4 + r) * EMBED +
              h * HDIM + n * 16 + fr] = f2bf(o_[n][r] * inv[r]);
}

// ---------------------------------------------------------------------------
// Launch
// ---------------------------------------------------------------------------
extern "C" void kernel_launch(void* const* d_in, const int* in_sizes, int n_in,
                              void* d_out, int out_size, void* d_ws, size_t ws_size,
                              hipStream_t stream)
{
    const float* hidden  = (const float*)d_in[0];
    const float* context = (const float*)d_in[1];
    const float* cn_g = (const float*)d_in[2];
    const float* cn_b = (const float*)d_in[3];
    const float* wq_c = (const float*)d_in[4];
    const float* bq_c = (const float*)d_in[5];
    const float* wk_c = (const float*)d_in[6];
    const float* bk_c = (const float*)d_in[7];
    const float* wv_c = (const float*)d_in[8];
    const float* bv_c = (const float*)d_in[9];
    const float* wo_c = (const float*)d_in[10];
    const float* bo_c = (const float*)d_in[11];
    const float* bias_c = (const float*)d_in[12];
    const float* sn_g = (const float*)d_in[13];
    const float* sn_b = (const float*)d_in[14];
    const float* wq_s = (const float*)d_in[15];
    const float* bq_s = (const float*)d_in[16];
    const float* wk_s = (const float*)d_in[17];
    const float* bk_s = (const float*)d_in[18];
    const float* wv_s = (const float*)d_in[19];
    const float* bv_s = (const float*)d_in[20];
    const float* wo_s = (const float*)d_in[21];
    const float* bo_s = (const float*)d_in[22];
    const float* bias_s = (const float*)d_in[23];
    const float* fn_g = (const float*)d_in[24];
    const float* fn_b = (const float*)d_in[25];
    const float* w1 = (const float*)d_in[26];
    const float* b1 = (const float*)d_in[27];
    const float* w2 = (const float*)d_in[28];
    const float* b2 = (const float*)d_in[29];

    const size_t NTOK = (size_t)BATCH * SEQ;   // 8192
    const size_t NCTX = (size_t)BATCH * CTX;   // 2048
    const size_t TE = NTOK * EMBED;            // 6291456

    // ---- workspace layout (qbuf..obuf contiguous; fbuf aliases that span) ----
    char* p = (char*)d_ws;
    float* hbuf = (float*)p;                   p += TE * 4;
    unsigned short* xbuf = (unsigned short*)p; p += TE * 2;
    unsigned short* qbuf = (unsigned short*)p; p += TE * 2;
    unsigned short* kbuf = (unsigned short*)p; p += TE * 2;
    unsigned short* vbuf = (unsigned short*)p; p += TE * 2;
    unsigned short* obuf = (unsigned short*)p; p += TE * 2;
    unsigned short* ctxb = (unsigned short*)p; p += NCTX * CROSS * 2;
    unsigned short* wt_qc   = (unsigned short*)p; p += (size_t)EMBED * EMBED * 2;
    unsigned short* wt_kvc  = (unsigned short*)p; p += (size_t)2 * EMBED * CROSS * 2;
    unsigned short* wt_oc   = (unsigned short*)p; p += (size_t)EMBED * EMBED * 2;
    unsigned short* wt_qkvs = (unsigned short*)p; p += (size_t)3 * EMBED * EMBED * 2;
    unsigned short* wt_os   = (unsigned short*)p; p += (size_t)EMBED * EMBED * 2;
    unsigned short* wt_w1   = (unsigned short*)p; p += (size_t)EMBED * FFN_DIM * 2;
    unsigned short* wt_w2   = (unsigned short*)p; p += (size_t)FFN_DIM * EMBED * 2;
    unsigned short* fbuf = qbuf;   // [8192,3072] bf16 = q+k+v+o span exactly
    float* out = (float*)d_out;

    const dim3 blk(256);
    const float scale = 0.125f;
    const dim3 agrid(BATCH * (SEQ / 64) * HEADS);   // 1536

    // ---- weight prep (concat slices are contiguous rows of WT) ----
    transpose_cast_kernel<<<dim3(EMBED/32, EMBED/32), blk, 0, stream>>>(wq_c, wt_qc, EMBED, EMBED);
    transpose_cast_kernel<<<dim3(EMBED/32, CROSS/32), blk, 0, stream>>>(wk_c, wt_kvc, CROSS, EMBED);
    transpose_cast_kernel<<<dim3(EMBED/32, CROSS/32), blk, 0, stream>>>(
        wv_c, wt_kvc + (size_t)EMBED * CROSS, CROSS, EMBED);
    transpose_cast_kernel<<<dim3(EMBED/32, EMBED/32), blk, 0, stream>>>(wo_c, wt_oc, EMBED, EMBED);
    transpose_cast_kernel<<<dim3(EMBED/32, EMBED/32), blk, 0, stream>>>(wq_s, wt_qkvs, EMBED, EMBED);
    transpose_cast_kernel<<<dim3(EMBED/32, EMBED/32), blk, 0, stream>>>(
        wk_s, wt_qkvs + (size_t)EMBED * EMBED, EMBED, EMBED);
    transpose_cast_kernel<<<dim3(EMBED/32, EMBED/32), blk, 0, stream>>>(
        wv_s, wt_qkvs + (size_t)2 * EMBED * EMBED, EMBED, EMBED);
    transpose_cast_kernel<<<dim3(EMBED/32, EMBED/32), blk, 0, stream>>>(wo_s, wt_os, EMBED, EMBED);
    transpose_cast_kernel<<<dim3(FFN_DIM/32, EMBED/32), blk, 0, stream>>>(w1, wt_w1, EMBED, FFN_DIM);
    transpose_cast_kernel<<<dim3(EMBED/32, FFN_DIM/32), blk, 0, stream>>>(w2, wt_w2, FFN_DIM, EMBED);
    cast_bf16_kernel<<<(int)(NCTX * CROSS / 1024), blk, 0, stream>>>(
        context, ctxb, (int)(NCTX * CROSS));

    // ---- cross attention block ----
    ln_kernel<<<(int)NTOK, blk, 0, stream>>>(hidden, cn_g, cn_b, xbuf);
    gemm_mfma_kernel<1,0><<<dim3(EMBED/128, NTOK/128), blk, 0, stream>>>(
        xbuf, wt_qc, bq_c, nullptr, qbuf, NTOK, EMBED, EMBED);
    gemm_qkv_kernel<<<dim3(2*EMBED/128, NCTX/128), blk, 0, stream>>>(
        ctxb, wt_kvc, bk_c, bv_c, nullptr, kbuf, nullptr, vbuf,
        NCTX, CROSS, 8, 1);                                      // parts: K, V^T
    flash_mfma_kernel<CTX><<<agrid, blk, 0, stream>>>(
        qbuf, kbuf, vbuf, bias_c, obuf, scale);
    gemm_mfma_kernel<0,0><<<dim3(EMBED/128, NTOK/128), blk, 0, stream>>>(
        obuf, wt_oc, bo_c, hidden, hbuf, NTOK, EMBED, EMBED);

    // ---- self attention block ----
    ln_kernel<<<(int)NTOK, blk, 0, stream>>>(hbuf, sn_g, sn_b, xbuf);
    gemm_qkv_kernel<<<dim3(3*EMBED/128, NTOK/128), blk, 0, stream>>>(
        xbuf, wt_qkvs, bq_s, bk_s, bv_s, qbuf, kbuf, vbuf,
        NTOK, EMBED, 10, 2);                                     // parts: Q, K, V^T
    flash_mfma_kernel<SEQ><<<agrid, blk, 0, stream>>>(
        qbuf, kbuf, vbuf, bias_s, obuf, scale);
    gemm_mfma_kernel<0,0><<<dim3(EMBED/128, NTOK/128), blk, 0, stream>>>(
        obuf, wt_os, bo_s, hbuf, hbuf, NTOK, EMBED, EMBED);  // in-place resid

    // ---- FFN ----
    ln_kernel<<<(int)NTOK, blk, 0, stream>>>(hbuf, fn_g, fn_b, xbuf);
    gemm_mfma_kernel<1,1><<<dim3(FFN_DIM/128, NTOK/128), blk, 0, stream>>>(
        xbuf, wt_w1, b1, nullptr, fbuf, NTOK, FFN_DIM, EMBED);
    gemm_mfma_kernel<0,0><<<dim3(EMBED/128, NTOK/128), blk, 0, stream>>>(
        fbuf, wt_w2, b2, nullptr, out, NTOK, EMBED, FFN_DIM);
}

// Round 12
// 742.467 us; speedup vs baseline: 14.0318x; 1.0937x over previous
//
#include <hip/hip_runtime.h>
#include <hip/hip_bf16.h>
#include <math.h>

#define EMBED 768
#define CROSS 512
#define HEADS 12
#define HDIM  64
#define FFN_DIM 3072
#define BATCH 8
#define SEQ   1024
#define CTX   256
#define LN_EPS 1e-5f

using f32x4 = __attribute__((ext_vector_type(4))) float;
using s16x8 = __attribute__((ext_vector_type(8))) short;   // 8 bf16 in 4 VGPRs

// float -> bf16 (RNE), bit-trick
__device__ __forceinline__ unsigned short f2bf(float f) {
    union { float f; unsigned u; } x{f};
    const unsigned r = x.u + 0x7fffu + ((x.u >> 16) & 1u);
    return (unsigned short)(r >> 16);
}

__device__ __forceinline__ void gl16(const void* g, void* l) {
    __builtin_amdgcn_global_load_lds(
        (const __attribute__((address_space(1))) void*)g,
        (__attribute__((address_space(3))) void*)l, 16, 0, 0);
}

__device__ __forceinline__ float gelu_f(float x) {
    const float c = 0.7978845608028654f;  // sqrt(2/pi)
    return 0.5f * x * (1.0f + tanhf(c * (x + 0.044715f * x * x * x)));
}

// ---------------------------------------------------------------------------
// Weight prep: W[K,N] fp32 -> WT[N,K] bf16 (transposed, K-contiguous)
// ---------------------------------------------------------------------------
__global__ __launch_bounds__(256) void transpose_cast_kernel(
    const float* __restrict__ W, unsigned short* __restrict__ WT, int K, int N)
{
    __shared__ float T[32][33];
    const int k0 = blockIdx.y * 32, n0 = blockIdx.x * 32;
    const int t = threadIdx.x;
    const int r = t >> 3, c4 = (t & 7) * 4;
    const float4 v = *(const float4*)(W + (size_t)(k0 + r) * N + n0 + c4);
    T[r][c4 + 0] = v.x; T[r][c4 + 1] = v.y; T[r][c4 + 2] = v.z; T[r][c4 + 3] = v.w;
    __syncthreads();
    ushort4 o;
    o.x = f2bf(T[c4 + 0][r]); o.y = f2bf(T[c4 + 1][r]);
    o.z = f2bf(T[c4 + 2][r]); o.w = f2bf(T[c4 + 3][r]);
    *(ushort4*)(WT + (size_t)(n0 + r) * K + k0 + c4) = o;
}

// elementwise fp32 -> bf16
__global__ __launch_bounds__(256) void cast_bf16_kernel(
    const float* __restrict__ x, unsigned short* __restrict__ y, int n)
{
    const int i = (blockIdx.x * 256 + threadIdx.x) * 4;
    if (i < n) {
        const float4 v = *(const float4*)(x + i);
        ushort4 o{f2bf(v.x), f2bf(v.y), f2bf(v.z), f2bf(v.w)};
        *(ushort4*)(y + i) = o;
    }
}

// ---------------------------------------------------------------------------
// LayerNorm over 768, writes bf16. One block per row.
// ---------------------------------------------------------------------------
__global__ __launch_bounds__(256) void ln_kernel(
    const float* __restrict__ x, const float* __restrict__ g,
    const float* __restrict__ beta, unsigned short* __restrict__ y)
{
    __shared__ float red[256];
    const size_t row = blockIdx.x;
    const float* xr = x + row * EMBED;
    const int t = threadIdx.x;

    float v0 = xr[t], v1 = xr[t + 256], v2 = xr[t + 512];

    red[t] = v0 + v1 + v2;
    __syncthreads();
    for (int off = 128; off > 0; off >>= 1) {
        if (t < off) red[t] += red[t + off];
        __syncthreads();
    }
    const float mu = red[0] * (1.0f / (float)EMBED);
    __syncthreads();

    const float d0 = v0 - mu, d1 = v1 - mu, d2 = v2 - mu;
    red[t] = d0 * d0 + d1 * d1 + d2 * d2;
    __syncthreads();
    for (int off = 128; off > 0; off >>= 1) {
        if (t < off) red[t] += red[t + off];
        __syncthreads();
    }
    const float var = red[0] * (1.0f / (float)EMBED);
    const float rstd = rsqrtf(var + LN_EPS);

    unsigned short* yr = y + row * EMBED;
    yr[t]       = f2bf(d0 * rstd * g[t]       + beta[t]);
    yr[t + 256] = f2bf(d1 * rstd * g[t + 256] + beta[t + 256]);
    yr[t + 512] = f2bf(d2 * rstd * g[t + 512] + beta[t + 512]);
}

// ---------------------------------------------------------------------------
// bf16 MFMA GEMM, 128x128 tile, BK=32, 4 waves.
// MODE: 0 = f32 out, 1 = bf16 out.
// ---------------------------------------------------------------------------
template <int MODE, int DO_GELU>
__global__ __launch_bounds__(256) void gemm_mfma_kernel(
    const unsigned short* __restrict__ A,   // [M,K]
    const unsigned short* __restrict__ WT,  // [N,K]
    const float* __restrict__ bias,         // [N]
    const float* __restrict__ resid,        // [M,N] or null
    void* __restrict__ Cv, int M, int N, int K)
{
    __shared__ unsigned short As[128][32];
    __shared__ unsigned short Bs[128][32];

    const int t = threadIdx.x;
    const int l = t & 63;
    const int w = t >> 6;
    const int m0 = blockIdx.y * 128;
    const int n0 = blockIdx.x * 128;
    const int wm = (w >> 1) * 64;
    const int wn = (w & 1) * 64;

    const int sr = t >> 2;
    const int sc = t & 3;

    f32x4 acc[4][4] = {};

    const unsigned short* Ap0 = A  + (size_t)(m0 + sr) * K + sc * 8;
    const unsigned short* Ap1 = Ap0 + (size_t)64 * K;
    const unsigned short* Bp0 = WT + (size_t)(n0 + sr) * K + sc * 8;
    const unsigned short* Bp1 = Bp0 + (size_t)64 * K;

    const int fr = l & 15;
    const int kb = (l >> 4) * 8;

    for (int k0 = 0; k0 < K; k0 += 32) {
        gl16(Ap0 + k0, &As[sr][sc * 8]);
        gl16(Ap1 + k0, &As[sr + 64][sc * 8]);
        gl16(Bp0 + k0, &Bs[sr][sc * 8]);
        gl16(Bp1 + k0, &Bs[sr + 64][sc * 8]);
        __syncthreads();

        s16x8 af[4], bf[4];
#pragma unroll
        for (int i = 0; i < 4; ++i) af[i] = *(const s16x8*)&As[wm + i * 16 + fr][kb];
#pragma unroll
        for (int j = 0; j < 4; ++j) bf[j] = *(const s16x8*)&Bs[wn + j * 16 + fr][kb];
#pragma unroll
        for (int i = 0; i < 4; ++i)
#pragma unroll
            for (int j = 0; j < 4; ++j)
                acc[i][j] = __builtin_amdgcn_mfma_f32_16x16x32_bf16(
                    af[i], bf[j], acc[i][j], 0, 0, 0);
        __syncthreads();
    }

    const int rg = (l >> 4) * 4;
#pragma unroll
    for (int j = 0; j < 4; ++j) {
        const int col = n0 + wn + j * 16 + fr;
        const float bia = bias[col];
#pragma unroll
        for (int i = 0; i < 4; ++i) {
#pragma unroll
            for (int r = 0; r < 4; ++r) {
                const int row = m0 + wm + i * 16 + rg + r;
                float v = acc[i][j][r] + bia;
                if (resid) v += resid[(size_t)row * N + col];
                if (DO_GELU) v = gelu_f(v);
                if (MODE == 0) {
                    ((float*)Cv)[(size_t)row * N + col] = v;
                } else {
                    ((unsigned short*)Cv)[(size_t)row * N + col] = f2bf(v);
                }
            }
        }
    }
}

// ---------------------------------------------------------------------------
// Fused projection GEMM over concatenated weights WT[Ntot,K] (Ntot = 768*P).
// 768 % 128 == 0, so each 128-col block lies in exactly one part.
// part == vpart -> write V^T per head [b,h,d,k] (sklog = log2 seq len);
// else bf16 [M,768] to out0/out1. Bias selected per part (b0,b1,b2).
// ---------------------------------------------------------------------------
__global__ __launch_bounds__(256) void gemm_qkv_kernel(
    const unsigned short* __restrict__ A,   // [M,K]
    const unsigned short* __restrict__ WT,  // [Ntot,K] concat
    const float* __restrict__ b0, const float* __restrict__ b1,
    const float* __restrict__ b2,
    unsigned short* __restrict__ out0, unsigned short* __restrict__ out1,
    unsigned short* __restrict__ vt,
    int M, int K, int sklog, int vpart)
{
    __shared__ unsigned short As[128][32];
    __shared__ unsigned short Bs[128][32];

    const int t = threadIdx.x;
    const int l = t & 63;
    const int w = t >> 6;
    const int m0 = blockIdx.y * 128;
    const int n0 = blockIdx.x * 128;
    const int part = n0 / 768;
    const int nl0 = n0 - part * 768;
    const float* bias = (part == 0) ? b0 : ((part == 1) ? b1 : b2);
    const int wm = (w >> 1) * 64;
    const int wn = (w & 1) * 64;

    const int sr = t >> 2;
    const int sc = t & 3;

    f32x4 acc[4][4] = {};

    const unsigned short* Ap0 = A  + (size_t)(m0 + sr) * K + sc * 8;
    const unsigned short* Ap1 = Ap0 + (size_t)64 * K;
    const unsigned short* Bp0 = WT + (size_t)(n0 + sr) * K + sc * 8;
    const unsigned short* Bp1 = Bp0 + (size_t)64 * K;

    const int fr = l & 15;
    const int kb = (l >> 4) * 8;

    for (int k0 = 0; k0 < K; k0 += 32) {
        gl16(Ap0 + k0, &As[sr][sc * 8]);
        gl16(Ap1 + k0, &As[sr + 64][sc * 8]);
        gl16(Bp0 + k0, &Bs[sr][sc * 8]);
        gl16(Bp1 + k0, &Bs[sr + 64][sc * 8]);
        __syncthreads();

        s16x8 af[4], bf[4];
#pragma unroll
        for (int i = 0; i < 4; ++i) af[i] = *(const s16x8*)&As[wm + i * 16 + fr][kb];
#pragma unroll
        for (int j = 0; j < 4; ++j) bf[j] = *(const s16x8*)&Bs[wn + j * 16 + fr][kb];
#pragma unroll
        for (int i = 0; i < 4; ++i)
#pragma unroll
            for (int j = 0; j < 4; ++j)
                acc[i][j] = __builtin_amdgcn_mfma_f32_16x16x32_bf16(
                    af[i], bf[j], acc[i][j], 0, 0, 0);
        __syncthreads();
    }

    const int rg = (l >> 4) * 4;
    unsigned short* outp = (part == 0) ? out0 : out1;
#pragma unroll
    for (int j = 0; j < 4; ++j) {
        const int nl = nl0 + wn + j * 16 + fr;
        const float bia = bias[nl];
#pragma unroll
        for (int i = 0; i < 4; ++i) {
#pragma unroll
            for (int r = 0; r < 4; ++r) {
                const int row = m0 + wm + i * 16 + rg + r;
                const float v = acc[i][j][r] + bia;
                if (part == vpart) {
                    const int bb = row >> sklog;
                    const int kk = row - (bb << sklog);
                    const int hh = nl >> 6;
                    const int dd = nl & 63;
                    vt[(((size_t)(bb * HEADS + hh) * 64 + dd) << sklog) + kk] = f2bf(v);
                } else {
                    outp[(size_t)row * 768 + nl] = f2bf(v);
                }
            }
        }
    }
}

// ---------------------------------------------------------------------------
// MFMA flash attention with T14 async-stage split.
// Block = 64 q-rows of one (b,h); 4 waves x 16 q-rows.
// Next K/V tile loaded to NAMED register variables (not arrays — arrays with
// cross-barrier live ranges spilled to scratch in R11: WRITE_SIZE 12->263MB)
// during compute, written to LDS after the closing barrier; bias prefetched
// before the QK MFMAs.
// ---------------------------------------------------------------------------
template <int SK>
__global__ __launch_bounds__(256) void flash_mfma_kernel(
    const unsigned short* __restrict__ Q, const unsigned short* __restrict__ K,
    const unsigned short* __restrict__ VT, const float* __restrict__ bias,
    unsigned short* __restrict__ O, float scale)
{
    __shared__ unsigned short Qs[64][72];
    __shared__ unsigned short Ks[64][72];
    __shared__ unsigned short Vts[64][72];
    __shared__ unsigned short Ps[64][72];

    // nwg = 8*16*12 = 1536; 192 per XCD, batch-fastest logical order
    const int g = blockIdx.x;
    const int L = (g & 7) * 192 + (g >> 3);
    const int b  = L & 7;
    const int qt = (L >> 3) & 15;
    const int h  = L >> 7;
    const int q0 = qt * 64;

    const int t  = threadIdx.x;
    const int l  = t & 63;
    const int w  = t >> 6;
    const int fr = l & 15;
    const int hi = l >> 4;

    const int str = t >> 3;        // staging row 0..31 (+32 second pass)
    const int stc = (t & 7) * 8;   // staging col (elements)

    const unsigned short* Kbase  = K + (size_t)(b * SK) * EMBED + h * HDIM + stc;
    const unsigned short* VTbase = VT + ((size_t)(b * HEADS + h) * 64) * SK + stc;

    // ---- stage Q ----
#pragma unroll
    for (int ps = 0; ps < 2; ++ps) {
        const int r = str + ps * 32;
        *(uint4*)&Qs[r][stc] =
            *(const uint4*)(Q + ((size_t)(b * SEQ) + q0 + r) * EMBED + h * HDIM + stc);
    }

    // ---- prologue: tile 0 to NAMED regs, then LDS ----
    uint4 kreg0 = *(const uint4*)(Kbase + (size_t)str * EMBED);
    uint4 kreg1 = *(const uint4*)(Kbase + (size_t)(str + 32) * EMBED);
    uint4 vreg0 = *(const uint4*)(VTbase + (size_t)str * SK);
    uint4 vreg1 = *(const uint4*)(VTbase + (size_t)(str + 32) * SK);
    *(uint4*)&Ks[str][stc]       = kreg0;
    *(uint4*)&Ks[str + 32][stc]  = kreg1;
    *(uint4*)&Vts[str][stc]      = vreg0;
    *(uint4*)&Vts[str + 32][stc] = vreg1;

    float m_[4], l_[4];
    f32x4 o_[4];
#pragma unroll
    for (int r = 0; r < 4; ++r) { m_[r] = -1e30f; l_[r] = 0.0f; }
#pragma unroll
    for (int n = 0; n < 4; ++n) o_[n] = f32x4{0.f, 0.f, 0.f, 0.f};

    const float* bbase = bias + ((size_t)h * SEQ + q0 + w * 16) * SK;
    __syncthreads();

    for (int k0 = 0; k0 < SK; k0 += 64) {
        const int kn = k0 + 64;
        // ---- issue NEXT-tile loads into named registers (T14 issue-early) ----
        if (kn < SK) {
            kreg0 = *(const uint4*)(Kbase + (size_t)(kn + str) * EMBED);
            kreg1 = *(const uint4*)(Kbase + (size_t)(kn + str + 32) * EMBED);
            vreg0 = *(const uint4*)(VTbase + (size_t)str * SK + kn);
            vreg1 = *(const uint4*)(VTbase + (size_t)(str + 32) * SK + kn);
        }

        // ---- bias prefetch for CURRENT tile ----
        float bre[4][4];
#pragma unroll
        for (int r = 0; r < 4; ++r)
#pragma unroll
            for (int j = 0; j < 4; ++j)
                bre[r][j] = bbase[(size_t)(hi * 4 + r) * SK + k0 + fr + 16 * j];

        // ---- QK^T: S[16q x 64k] per wave ----
        f32x4 s[4] = {};
#pragma unroll
        for (int ks = 0; ks < 2; ++ks) {
            const s16x8 aq = *(const s16x8*)&Qs[w * 16 + fr][ks * 32 + hi * 8];
#pragma unroll
            for (int j = 0; j < 4; ++j) {
                const s16x8 bk = *(const s16x8*)&Ks[j * 16 + fr][ks * 32 + hi * 8];
                s[j] = __builtin_amdgcn_mfma_f32_16x16x32_bf16(aq, bk, s[j], 0, 0, 0);
            }
        }

        // ---- online softmax; rows = hi*4 + r, cols = fr + 16j ----
        float corr[4];
#pragma unroll
        for (int r = 0; r < 4; ++r) {
            float v0 = s[0][r] * scale + bre[r][0];
            float v1 = s[1][r] * scale + bre[r][1];
            float v2 = s[2][r] * scale + bre[r][2];
            float v3 = s[3][r] * scale + bre[r][3];
            float mx = fmaxf(fmaxf(v0, v1), fmaxf(v2, v3));
            mx = fmaxf(mx, __shfl_xor(mx, 1));
            mx = fmaxf(mx, __shfl_xor(mx, 2));
            mx = fmaxf(mx, __shfl_xor(mx, 4));
            mx = fmaxf(mx, __shfl_xor(mx, 8));
            const float mnew = fmaxf(m_[r], mx);
            const float c = __expf(m_[r] - mnew);
            m_[r] = mnew;
            const float p0 = __expf(v0 - mnew);
            const float p1 = __expf(v1 - mnew);
            const float p2 = __expf(v2 - mnew);
            const float p3 = __expf(v3 - mnew);
            float psum = p0 + p1 + p2 + p3;
            psum += __shfl_xor(psum, 1);
            psum += __shfl_xor(psum, 2);
            psum += __shfl_xor(psum, 4);
            psum += __shfl_xor(psum, 8);
            l_[r] = l_[r] * c + psum;
            corr[r] = c;
            const int prow = w * 16 + hi * 4 + r;
            Ps[prow][fr]      = f2bf(p0);
            Ps[prow][fr + 16] = f2bf(p1);
            Ps[prow][fr + 32] = f2bf(p2);
            Ps[prow][fr + 48] = f2bf(p3);
        }
#pragma unroll
        for (int n = 0; n < 4; ++n)
#pragma unroll
            for (int r = 0; r < 4; ++r) o_[n][r] *= corr[r];

        // ---- PV: O[16q x 64d] per wave (P wave-local) ----
#pragma unroll
        for (int ks = 0; ks < 2; ++ks) {
            const s16x8 ap = *(const s16x8*)&Ps[w * 16 + fr][ks * 32 + hi * 8];
#pragma unroll
            for (int n = 0; n < 4; ++n) {
                const s16x8 bv = *(const s16x8*)&Vts[n * 16 + fr][ks * 32 + hi * 8];
                o_[n] = __builtin_amdgcn_mfma_f32_16x16x32_bf16(ap, bv, o_[n], 0, 0, 0);
            }
        }
        __syncthreads();   // all reads of Ks/Vts done

        // ---- write NEXT tile regs -> LDS (T14 write-late) ----
        if (kn < SK) {
            *(uint4*)&Ks[str][stc]       = kreg0;
            *(uint4*)&Ks[str + 32][stc]  = kreg1;
            *(uint4*)&Vts[str][stc]      = vreg0;
            *(uint4*)&Vts[str + 32][stc] = vreg1;
            __syncthreads();
        }
    }

    // ---- finalize + store (rows hi*4+r, cols fr+16n) ----
    float inv[4];
#pragma unroll
    for (int r = 0; r < 4; ++r) inv[r] = 1.0f / l_[r];
#pragma unroll
    for (int n = 0; n < 4; ++n)
#pragma unroll
        for (int r = 0; r < 4; ++r)
            O[((size_t)(b * SEQ) + q0 + w * 16 + hi * 4 + r) * EMBED +
              h * HDIM + n * 16 + fr] = f2bf(o_[n][r] * inv[r]);
}

// ---------------------------------------------------------------------------
// Launch
// ---------------------------------------------------------------------------
extern "C" void kernel_launch(void* const* d_in, const int* in_sizes, int n_in,
                              void* d_out, int out_size, void* d_ws, size_t ws_size,
                              hipStream_t stream)
{
    const float* hidden  = (const float*)d_in[0];
    const float* context = (const float*)d_in[1];
    const float* cn_g = (const float*)d_in[2];
    const float* cn_b = (const float*)d_in[3];
    const float* wq_c = (const float*)d_in[4];
    const float* bq_c = (const float*)d_in[5];
    const float* wk_c = (const float*)d_in[6];
    const float* bk_c = (const float*)d_in[7];
    const float* wv_c = (const float*)d_in[8];
    const float* bv_c = (const float*)d_in[9];
    const float* wo_c = (const float*)d_in[10];
    const float* bo_c = (const float*)d_in[11];
    const float* bias_c = (const float*)d_in[12];
    const float* sn_g = (const float*)d_in[13];
    const float* sn_b = (const float*)d_in[14];
    const float* wq_s = (const float*)d_in[15];
    const float* bq_s = (const float*)d_in[16];
    const float* wk_s = (const float*)d_in[17];
    const float* bk_s = (const float*)d_in[18];
    const float* wv_s = (const float*)d_in[19];
    const float* bv_s = (const float*)d_in[20];
    const float* wo_s = (const float*)d_in[21];
    const float* bo_s = (const float*)d_in[22];
    const float* bias_s = (const float*)d_in[23];
    const float* fn_g = (const float*)d_in[24];
    const float* fn_b = (const float*)d_in[25];
    const float* w1 = (const float*)d_in[26];
    const float* b1 = (const float*)d_in[27];
    const float* w2 = (const float*)d_in[28];
    const float* b2 = (const float*)d_in[29];

    const size_t NTOK = (size_t)BATCH * SEQ;   // 8192
    const size_t NCTX = (size_t)BATCH * CTX;   // 2048
    const size_t TE = NTOK * EMBED;            // 6291456

    // ---- workspace layout (qbuf..obuf contiguous; fbuf aliases that span) ----
    char* p = (char*)d_ws;
    float* hbuf = (float*)p;                   p += TE * 4;
    unsigned short* xbuf = (unsigned short*)p; p += TE * 2;
    unsigned short* qbuf = (unsigned short*)p; p += TE * 2;
    unsigned short* kbuf = (unsigned short*)p; p += TE * 2;
    unsigned short* vbuf = (unsigned short*)p; p += TE * 2;
    unsigned short* obuf = (unsigned short*)p; p += TE * 2;
    unsigned short* ctxb = (unsigned short*)p; p += NCTX * CROSS * 2;
    unsigned short* wt_qc   = (unsigned short*)p; p += (size_t)EMBED * EMBED * 2;
    unsigned short* wt_kvc  = (unsigned short*)p; p += (size_t)2 * EMBED * CROSS * 2;
    unsigned short* wt_oc   = (unsigned short*)p; p += (size_t)EMBED * EMBED * 2;
    unsigned short* wt_qkvs = (unsigned short*)p; p += (size_t)3 * EMBED * EMBED * 2;
    unsigned short* wt_os   = (unsigned short*)p; p += (size_t)EMBED * EMBED * 2;
    unsigned short* wt_w1   = (unsigned short*)p; p += (size_t)EMBED * FFN_DIM * 2;
    unsigned short* wt_w2   = (unsigned short*)p; p += (size_t)FFN_DIM * EMBED * 2;
    unsigned short* fbuf = qbuf;   // [8192,3072] bf16 = q+k+v+o span exactly
    float* out = (float*)d_out;

    const dim3 blk(256);
    const float scale = 0.125f;
    const dim3 agrid(BATCH * (SEQ / 64) * HEADS);   // 1536

    // ---- weight prep (concat slices are contiguous rows of WT) ----
    transpose_cast_kernel<<<dim3(EMBED/32, EMBED/32), blk, 0, stream>>>(wq_c, wt_qc, EMBED, EMBED);
    transpose_cast_kernel<<<dim3(EMBED/32, CROSS/32), blk, 0, stream>>>(wk_c, wt_kvc, CROSS, EMBED);
    transpose_cast_kernel<<<dim3(EMBED/32, CROSS/32), blk, 0, stream>>>(
        wv_c, wt_kvc + (size_t)EMBED * CROSS, CROSS, EMBED);
    transpose_cast_kernel<<<dim3(EMBED/32, EMBED/32), blk, 0, stream>>>(wo_c, wt_oc, EMBED, EMBED);
    transpose_cast_kernel<<<dim3(EMBED/32, EMBED/32), blk, 0, stream>>>(wq_s, wt_qkvs, EMBED, EMBED);
    transpose_cast_kernel<<<dim3(EMBED/32, EMBED/32), blk, 0, stream>>>(
        wk_s, wt_qkvs + (size_t)EMBED * EMBED, EMBED, EMBED);
    transpose_cast_kernel<<<dim3(EMBED/32, EMBED/32), blk, 0, stream>>>(
        wv_s, wt_qkvs + (size_t)2 * EMBED * EMBED, EMBED, EMBED);
    transpose_cast_kernel<<<dim3(EMBED/32, EMBED/32), blk, 0, stream>>>(wo_s, wt_os, EMBED, EMBED);
    transpose_cast_kernel<<<dim3(FFN_DIM/32, EMBED/32), blk, 0, stream>>>(w1, wt_w1, EMBED, FFN_DIM);
    transpose_cast_kernel<<<dim3(EMBED/32, FFN_DIM/32), blk, 0, stream>>>(w2, wt_w2, FFN_DIM, EMBED);
    cast_bf16_kernel<<<(int)(NCTX * CROSS / 1024), blk, 0, stream>>>(
        context, ctxb, (int)(NCTX * CROSS));

    // ---- cross attention block ----
    ln_kernel<<<(int)NTOK, blk, 0, stream>>>(hidden, cn_g, cn_b, xbuf);
    gemm_mfma_kernel<1,0><<<dim3(EMBED/128, NTOK/128), blk, 0, stream>>>(
        xbuf, wt_qc, bq_c, nullptr, qbuf, NTOK, EMBED, EMBED);
    gemm_qkv_kernel<<<dim3(2*EMBED/128, NCTX/128), blk, 0, stream>>>(
        ctxb, wt_kvc, bk_c, bv_c, nullptr, kbuf, nullptr, vbuf,
        NCTX, CROSS, 8, 1);                                      // parts: K, V^T
    flash_mfma_kernel<CTX><<<agrid, blk, 0, stream>>>(
        qbuf, kbuf, vbuf, bias_c, obuf, scale);
    gemm_mfma_kernel<0,0><<<dim3(EMBED/128, NTOK/128), blk, 0, stream>>>(
        obuf, wt_oc, bo_c, hidden, hbuf, NTOK, EMBED, EMBED);

    // ---- self attention block ----
    ln_kernel<<<(int)NTOK, blk, 0, stream>>>(hbuf, sn_g, sn_b, xbuf);
    gemm_qkv_kernel<<<dim3(3*EMBED/128, NTOK/128), blk, 0, stream>>>(
        xbuf, wt_qkvs, bq_s, bk_s, bv_s, qbuf, kbuf, vbuf,
        NTOK, EMBED, 10, 2);                                     // parts: Q, K, V^T
    flash_mfma_kernel<SEQ><<<agrid, blk, 0, stream>>>(
        qbuf, kbuf, vbuf, bias_s, obuf, scale);
    gemm_mfma_kernel<0,0><<<dim3(EMBED/128, NTOK/128), blk, 0, stream>>>(
        obuf, wt_os, bo_s, hbuf, hbuf, NTOK, EMBED, EMBED);  // in-place resid

    // ---- FFN ----
    ln_kernel<<<(int)NTOK, blk, 0, stream>>>(hbuf, fn_g, fn_b, xbuf);
    gemm_mfma_kernel<1,1><<<dim3(FFN_DIM/128, NTOK/128), blk, 0, stream>>>(
        xbuf, wt_w1, b1, nullptr, fbuf, NTOK, FFN_DIM, EMBED);
    gemm_mfma_kernel<0,0><<<dim3(EMBED/128, NTOK/128), blk, 0, stream>>>(
        fbuf, wt_w2, b2, nullptr, out, NTOK, EMBED, FFN_DIM);
}